// Round 1
// baseline (6121.352 us; speedup 1.0000x reference)
//
#include <hip/hip_runtime.h>
#include <math.h>

#define D_MODEL 256
#define NH 8
#define DK 32
#define DFF 1024
#define NLAYERS 6
#define B_ 8
#define L_ 1024
#define NR (B_*L_)          // 8192 rows
#define TOPK 256            // L/4
#define LNEPS 1e-5f

// ---------------- wave helpers (wave64) ----------------
__device__ __forceinline__ float wsum(float v){
  #pragma unroll
  for(int o=32;o>0;o>>=1) v += __shfl_xor(v,o,64);
  return v;
}
__device__ __forceinline__ float wmax(float v){
  #pragma unroll
  for(int o=32;o>0;o>>=1) v = fmaxf(v,__shfl_xor(v,o,64));
  return v;
}
__device__ __forceinline__ int wisum(int v){
  #pragma unroll
  for(int o=32;o>0;o>>=1) v += __shfl_xor(v,o,64);
  return v;
}

// ---------------- embed: h = x@in_w + in_b + pe ----------------
__global__ __launch_bounds__(256) void embed_kernel(
    const float* __restrict__ x, const float* __restrict__ in_w,
    const float* __restrict__ in_b, float* __restrict__ h)
{
  int tid = blockIdx.x*256 + threadIdx.x;   // NR*64 threads total
  int n  = tid >> 6;
  int d0 = (tid & 63) << 2;
  int l  = n & (L_-1);
  float x0 = x[2*n], x1 = x[2*n+1];
  const float kf = -0.07195578415606394f;   // -ln(10000)/128
  float pe[4];
  #pragma unroll
  for(int ii=0; ii<2; ++ii){
    int i = (d0>>1) + ii;                   // pair index
    float dv  = expf((float)i * kf);
    float ang = (float)l * dv;
    pe[2*ii]   = sinf(ang);
    pe[2*ii+1] = cosf(ang);
  }
  float4 w0 = *(const float4*)(in_w + d0);
  float4 w1 = *(const float4*)(in_w + D_MODEL + d0);
  float4 bb = *(const float4*)(in_b + d0);
  float4 o;
  o.x = x0*w0.x + x1*w1.x + bb.x + pe[0];
  o.y = x0*w0.y + x1*w1.y + bb.y + pe[1];
  o.z = x0*w0.z + x1*w1.z + bb.z + pe[2];
  o.w = x0*w0.w + x1*w1.w + bb.w + pe[3];
  *(float4*)(h + (size_t)n*D_MODEL + d0) = o;
}

// ---------------- LayerNorm: wave per row (D=256, 4 floats/lane) ----------------
// ADD=false: out = LN(in)*g+b   ADD=true: out += LN(in)*g+b  (out!=in)
template<bool ADD>
__global__ __launch_bounds__(256) void ln_kernel(
    const float* __restrict__ in, const float* __restrict__ g,
    const float* __restrict__ b, float* __restrict__ out)
{
  int wave = threadIdx.x >> 6, lane = threadIdx.x & 63;
  int row = blockIdx.x*4 + wave;
  float4 v = ((const float4*)(in + (size_t)row*D_MODEL))[lane];
  float s  = v.x+v.y+v.z+v.w;
  float sq = v.x*v.x+v.y*v.y+v.z*v.z+v.w*v.w;
  s = wsum(s); sq = wsum(sq);
  float mean = s*(1.f/D_MODEL);
  float var  = sq*(1.f/D_MODEL) - mean*mean;
  float rstd = 1.f/sqrtf(var + LNEPS);
  float4 gv = ((const float4*)g)[lane];
  float4 bv = ((const float4*)b)[lane];
  float4 o;
  o.x = (v.x-mean)*rstd*gv.x + bv.x;
  o.y = (v.y-mean)*rstd*gv.y + bv.y;
  o.z = (v.z-mean)*rstd*gv.z + bv.z;
  o.w = (v.w-mean)*rstd*gv.w + bv.w;
  float4* op = (float4*)(out + (size_t)row*D_MODEL) + lane;
  if (ADD){ float4 hv = *op; o.x+=hv.x; o.y+=hv.y; o.z+=hv.z; o.w+=hv.w; }
  *op = o;
}

// ---------------- generic fp32 tiled GEMM: C = A[MxK] @ B[KxN] (+bias)(+resid)(+=C)(A*=vol) ----------------
// 64x64 tile, BK=16, 256 threads, 4x4 microtile per thread.
template<bool BIAS, bool RESID, bool ACCUM, bool ASCALE>
__global__ __launch_bounds__(256) void gemm_tiled(
    const float* __restrict__ A, const float* __restrict__ Bm,
    const float* __restrict__ bias, const float* __restrict__ resid,
    const float* __restrict__ asc, float* __restrict__ C,
    int M, int N, int K)
{
  __shared__ __align__(16) float As[16][68];   // [k][m], +4 pad keeps rows 16B aligned
  __shared__ __align__(16) float Bs[16][68];   // [k][n]
  const int t  = threadIdx.x;
  const int m0 = blockIdx.y*64, n0 = blockIdx.x*64;
  const int am = t>>2,  ak = (t&3)<<2;   // A staging: row am, k ak..ak+3
  const int bk = t>>4,  bn = (t&15)<<2;  // B staging: k bk, col bn..bn+3
  const int rg = (t>>4)<<2, cg = (t&15)<<2; // compute microtile origin
  const float* Ap = A  + (size_t)(m0+am)*K + ak;
  const float* Bp = Bm + (size_t)bk*N + n0 + bn;
  const float* vp = ASCALE ? (asc + (size_t)((m0+am)>>10)*K + ak) : nullptr;
  float acc[4][4] = {};
  for (int k0 = 0; k0 < K; k0 += 16){
    float4 a4 = *(const float4*)(Ap + k0);
    float4 b4 = *(const float4*)(Bp + (size_t)k0*N);
    if (ASCALE){
      a4.x *= vp[k0+0]; a4.y *= vp[k0+1]; a4.z *= vp[k0+2]; a4.w *= vp[k0+3];
    }
    As[ak+0][am]=a4.x; As[ak+1][am]=a4.y; As[ak+2][am]=a4.z; As[ak+3][am]=a4.w;
    *(float4*)&Bs[bk][bn] = b4;
    __syncthreads();
    #pragma unroll
    for (int kk=0; kk<16; ++kk){
      float4 av = *(const float4*)&As[kk][rg];
      float4 bv = *(const float4*)&Bs[kk][cg];
      acc[0][0]=fmaf(av.x,bv.x,acc[0][0]); acc[0][1]=fmaf(av.x,bv.y,acc[0][1]);
      acc[0][2]=fmaf(av.x,bv.z,acc[0][2]); acc[0][3]=fmaf(av.x,bv.w,acc[0][3]);
      acc[1][0]=fmaf(av.y,bv.x,acc[1][0]); acc[1][1]=fmaf(av.y,bv.y,acc[1][1]);
      acc[1][2]=fmaf(av.y,bv.z,acc[1][2]); acc[1][3]=fmaf(av.y,bv.w,acc[1][3]);
      acc[2][0]=fmaf(av.z,bv.x,acc[2][0]); acc[2][1]=fmaf(av.z,bv.y,acc[2][1]);
      acc[2][2]=fmaf(av.z,bv.z,acc[2][2]); acc[2][3]=fmaf(av.z,bv.w,acc[2][3]);
      acc[3][0]=fmaf(av.w,bv.x,acc[3][0]); acc[3][1]=fmaf(av.w,bv.y,acc[3][1]);
      acc[3][2]=fmaf(av.w,bv.z,acc[3][2]); acc[3][3]=fmaf(av.w,bv.w,acc[3][3]);
    }
    __syncthreads();
  }
  float4 bb = make_float4(0.f,0.f,0.f,0.f);
  if (BIAS) bb = *(const float4*)(bias + n0 + cg);
  #pragma unroll
  for (int i=0;i<4;++i){
    size_t off = (size_t)(m0+rg+i)*N + n0 + cg;
    float4 c = make_float4(acc[i][0],acc[i][1],acc[i][2],acc[i][3]);
    if (BIAS){ c.x+=bb.x; c.y+=bb.y; c.z+=bb.z; c.w+=bb.w; }
    if (RESID){ float4 r=*(const float4*)(resid+off); c.x+=r.x; c.y+=r.y; c.z+=r.z; c.w+=r.w; }
    if (ACCUM){ float4 r=*(const float4*)(C+off);     c.x+=r.x; c.y+=r.y; c.z+=r.z; c.w+=r.w; }
    *(float4*)(C+off) = c;
  }
}

// ---------------- fused ProbSparse attention ----------------
// One block = (b, h, 4 consecutive q rows); one wave per q row.
// scores -> exact top-256 threshold (bitwise binary search) -> softmax -> @V
__global__ __launch_bounds__(256) void attn_kernel(
    const float* __restrict__ qkv, float* __restrict__ obuf)
{
  __shared__ float kbuf[128*33];     // K/V chunk, stride 33 (2-way conflicts only)
  __shared__ float scw[4][1024];     // per-row scores, then weights
  __shared__ float qsh[4][32];
  const int t = threadIdx.x;
  const int wave = t>>6, lane = t&63;
  const int blk = blockIdx.x;
  const int bh = blk >> 8;           // L/4 = 256 q-tiles per (b,h)
  const int qt = blk & 255;
  const int b = bh >> 3, hh = bh & 7;
  const int ql = qt*4 + wave;
  const float* qb = qkv + (size_t)b*L_*768;
  if (t < 128){
    int r = t>>5, d = t&31;
    qsh[r][d] = qb[(size_t)(qt*4+r)*768 + hh*32 + d];
  }
  const float scale = 0.17677669529663687f;  // 1/sqrt(32)
  // ---- pass A: scores ----
  for (int c = 0; c < 8; ++c){
    __syncthreads();
    for (int p = t; p < 128*32; p += 256){
      int jj = p>>5, d = p&31;
      kbuf[jj*33+d] = qb[(size_t)(c*128+jj)*768 + 256 + hh*32 + d];
    }
    __syncthreads();
    #pragma unroll
    for (int half=0; half<2; ++half){
      int jl = half*64 + lane;
      float acc = 0.f;
      #pragma unroll
      for (int d=0; d<32; ++d)
        acc = fmaf(qsh[wave][d], kbuf[jl*33+d], acc);
      scw[wave][c*128 + jl] = acc*scale;
    }
  }
  // ---- exact top-k threshold: binary search on sortable uint keys ----
  float sc[16]; unsigned key[16];
  #pragma unroll
  for (int i=0;i<16;++i){
    sc[i] = scw[wave][i*64 + lane];
    unsigned u = __float_as_uint(sc[i]);
    key[i] = (u & 0x80000000u) ? ~u : (u | 0x80000000u);
  }
  unsigned long long lo=0, hi=0x100000000ULL;
  while (hi - lo > 1ULL){
    unsigned long long mid = (lo+hi)>>1;
    unsigned m32 = (unsigned)mid;
    int cnt = 0;
    #pragma unroll
    for (int i=0;i<16;++i) cnt += (key[i] >= m32) ? 1 : 0;
    cnt = wisum(cnt);
    if (cnt >= TOPK) lo = mid; else hi = mid;
  }
  const unsigned thr = (unsigned)lo;  // key of the 256th-largest score (exact)
  // ---- softmax over kept set ----
  float m = sc[0];
  #pragma unroll
  for (int i=1;i<16;++i) m = fmaxf(m, sc[i]);
  m = wmax(m);
  float sum = 0.f;
  #pragma unroll
  for (int i=0;i<16;++i){
    float wv = (key[i] >= thr) ? expf(sc[i]-m) : 0.f;
    scw[wave][i*64+lane] = wv;
    sum += wv;
  }
  sum = wsum(sum);
  const float inv = 1.f/sum;
  // ---- pass B: o = (w @ V) * inv ----
  float oacc = 0.f;
  const int d = lane & 31, ph = lane >> 5;
  for (int c = 0; c < 8; ++c){
    __syncthreads();
    for (int p = t; p < 128*32; p += 256){
      int jj = p>>5, dd = p&31;
      kbuf[jj*33+dd] = qb[(size_t)(c*128+jj)*768 + 512 + hh*32 + dd];
    }
    __syncthreads();
    #pragma unroll
    for (int jj=0; jj<128; jj+=2){
      int jl = jj + ph;
      oacc = fmaf(scw[wave][c*128+jl], kbuf[jl*33+d], oacc);
    }
  }
  oacc += __shfl_xor(oacc, 32, 64);
  if (ph == 0)
    obuf[(size_t)(b*L_+ql)*D_MODEL + hh*32 + d] = oacc * inv;
}

// ---------------- Volatilite vol: std over L per (b, ff-col) ----------------
__global__ __launch_bounds__(256) void vol_kernel(
    const float* __restrict__ f, float* __restrict__ vol)
{
  // grid: 8 b * 16 col-blocks of 64
  int b  = blockIdx.x >> 4, cb = blockIdx.x & 15;
  int cl = threadIdx.x & 63;
  int col = cb*64 + cl;
  int sl  = threadIdx.x >> 6;   // 0..3 L-slice
  const float* fb = f + (size_t)b*L_*DFF + col;
  float s = 0.f, sq = 0.f;
  for (int l = sl*256; l < sl*256+256; ++l){
    float v = fb[(size_t)l*DFF];
    s += v; sq += v*v;
  }
  __shared__ float ps[4][64], pq[4][64];
  ps[sl][cl] = s; pq[sl][cl] = sq;
  __syncthreads();
  if (threadIdx.x < 64){
    float st = ps[0][cl]+ps[1][cl]+ps[2][cl]+ps[3][cl];
    float qt = pq[0][cl]+pq[1][cl]+pq[2][cl]+pq[3][cl];
    float mean = st*(1.f/L_);
    float var  = qt*(1.f/L_) - mean*mean;
    vol[(size_t)b*DFF + col] = sqrtf(fmaxf(var, 0.f));
  }
}

// ---------------- launch ----------------
extern "C" void kernel_launch(void* const* d_in, const int* in_sizes, int n_in,
                              void* d_out, int out_size, void* d_ws, size_t ws_size,
                              hipStream_t stream) {
  const float* x     = (const float*)d_in[0];
  const float* in_w  = (const float*)d_in[1];
  const float* in_b  = (const float*)d_in[2];
  const float* ln1_g = (const float*)d_in[3];
  const float* ln1_b = (const float*)d_in[4];
  const float* qkv_w = (const float*)d_in[5];
  const float* qkv_b = (const float*)d_in[6];
  const float* out_w = (const float*)d_in[7];
  const float* out_b = (const float*)d_in[8];
  const float* lna_g = (const float*)d_in[9];
  const float* lna_b = (const float*)d_in[10];
  const float* ln2_g = (const float*)d_in[11];
  const float* ln2_b = (const float*)d_in[12];
  const float* ff1_w = (const float*)d_in[13];
  const float* ff1_b = (const float*)d_in[14];
  const float* ff2_w = (const float*)d_in[15];
  const float* ff2_b = (const float*)d_in[16];
  const float* lnf_g = (const float*)d_in[17];
  const float* lnf_b = (const float*)d_in[18];
  float* out = (float*)d_out;

  char* ws = (char*)d_ws;
  float* h   = (float*)(ws);                       // 8 MB
  float* s2  = (float*)(ws + (size_t)( 8<<20));    // 8 MB
  float* big = (float*)(ws + (size_t)(16<<20));    // 32 MB: qkv (24MB) then f (32MB)
  float* tb  = (float*)(ws + (size_t)(40<<20));    // 8 MB  (dead before f is written)
  float* ob  = (float*)(ws + (size_t)(48<<20));    // 8 MB
  float* vol = (float*)(ws + (size_t)(56<<20));    // 32 KB

  embed_kernel<<<NR*64/256, 256, 0, stream>>>(x, in_w, in_b, h);

  for (int layer = 0; layer < NLAYERS; ++layer){
    // s2 = LN(h)
    ln_kernel<false><<<NR/4, 256, 0, stream>>>(h, ln1_g, ln1_b, s2);
    // qkv = s2 @ qkv_w + qkv_b
    {
      dim3 g(768/64, NR/64);
      gemm_tiled<true,false,false,false><<<g, 256, 0, stream>>>(
          s2, qkv_w, qkv_b, nullptr, nullptr, big, NR, 768, D_MODEL);
    }
    // ob = ProbSparse attention
    attn_kernel<<<B_*NH*(L_/4), 256, 0, stream>>>(big, ob);
    // tb = ob @ out_w + out_b + s2
    {
      dim3 g(256/64, NR/64);
      gemm_tiled<true,true,false,false><<<g, 256, 0, stream>>>(
          ob, out_w, out_b, s2, nullptr, tb, NR, D_MODEL, D_MODEL);
    }
    // h += LN(tb)
    ln_kernel<true><<<NR/4, 256, 0, stream>>>(tb, lna_g, lna_b, h);
    // s2 = LN(h)
    ln_kernel<false><<<NR/4, 256, 0, stream>>>(h, ln2_g, ln2_b, s2);
    // f = s2 @ ff1_w + ff1_b
    {
      dim3 g(1024/64, NR/64);
      gemm_tiled<true,false,false,false><<<g, 256, 0, stream>>>(
          s2, ff1_w, ff1_b, nullptr, nullptr, big, NR, DFF, D_MODEL);
    }
    // vol = std over L of f
    vol_kernel<<<B_*16, 256, 0, stream>>>(big, vol);
    // h += (f * vol) @ ff2_w + ff2_b
    {
      dim3 g(256/64, NR/64);
      gemm_tiled<true,false,true,true><<<g, 256, 0, stream>>>(
          big, ff2_w, ff2_b, nullptr, vol, h, NR, D_MODEL, DFF);
    }
  }
  // out = LN(h)
  ln_kernel<false><<<NR/4, 256, 0, stream>>>(h, lnf_g, lnf_b, out);
}

// Round 2
// 3385.671 us; speedup vs baseline: 1.8080x; 1.8080x over previous
//
#include <hip/hip_runtime.h>
#include <math.h>

#define D_MODEL 256
#define NH 8
#define DK 32
#define DFF 1024
#define NLAYERS 6
#define B_ 8
#define L_ 1024
#define NR (B_*L_)          // 8192 rows
#define TOPK 256            // L/4
#define LNEPS 1e-5f

typedef __attribute__((ext_vector_type(8))) short bf16x8;
typedef __attribute__((ext_vector_type(4))) float f32x4;

// ---------------- wave helpers (wave64) ----------------
__device__ __forceinline__ float wsum(float v){
  #pragma unroll
  for(int o=32;o>0;o>>=1) v += __shfl_xor(v,o,64);
  return v;
}
__device__ __forceinline__ float wmax(float v){
  #pragma unroll
  for(int o=32;o>0;o>>=1) v = fmaxf(v,__shfl_xor(v,o,64));
  return v;
}
__device__ __forceinline__ short f2bf(float x){
  unsigned u = __float_as_uint(x);
  u += 0x7fffu + ((u>>16)&1u);   // RNE (finite inputs only)
  return (short)(u>>16);
}

// ---------------- embed: h = x@in_w + in_b + pe ----------------
__global__ __launch_bounds__(256) void embed_kernel(
    const float* __restrict__ x, const float* __restrict__ in_w,
    const float* __restrict__ in_b, float* __restrict__ h)
{
  int tid = blockIdx.x*256 + threadIdx.x;   // NR*64 threads total
  int n  = tid >> 6;
  int d0 = (tid & 63) << 2;
  int l  = n & (L_-1);
  float x0 = x[2*n], x1 = x[2*n+1];
  const float kf = -0.07195578415606394f;   // -ln(10000)/128
  float pe[4];
  #pragma unroll
  for(int ii=0; ii<2; ++ii){
    int i = (d0>>1) + ii;                   // pair index
    float dv  = expf((float)i * kf);
    float ang = (float)l * dv;
    pe[2*ii]   = sinf(ang);
    pe[2*ii+1] = cosf(ang);
  }
  float4 w0 = *(const float4*)(in_w + d0);
  float4 w1 = *(const float4*)(in_w + D_MODEL + d0);
  float4 bb = *(const float4*)(in_b + d0);
  float4 o;
  o.x = x0*w0.x + x1*w1.x + bb.x + pe[0];
  o.y = x0*w0.y + x1*w1.y + bb.y + pe[1];
  o.z = x0*w0.z + x1*w1.z + bb.z + pe[2];
  o.w = x0*w0.w + x1*w1.w + bb.w + pe[3];
  *(float4*)(h + (size_t)n*D_MODEL + d0) = o;
}

// ---------------- LayerNorm: wave per row (D=256, 4 floats/lane) ----------------
template<bool ADD>
__global__ __launch_bounds__(256) void ln_kernel(
    const float* __restrict__ in, const float* __restrict__ g,
    const float* __restrict__ b, float* __restrict__ out)
{
  int wave = threadIdx.x >> 6, lane = threadIdx.x & 63;
  int row = blockIdx.x*4 + wave;
  float4 v = ((const float4*)(in + (size_t)row*D_MODEL))[lane];
  float s  = v.x+v.y+v.z+v.w;
  float sq = v.x*v.x+v.y*v.y+v.z*v.z+v.w*v.w;
  s = wsum(s); sq = wsum(sq);
  float mean = s*(1.f/D_MODEL);
  float var  = sq*(1.f/D_MODEL) - mean*mean;
  float rstd = 1.f/sqrtf(var + LNEPS);
  float4 gv = ((const float4*)g)[lane];
  float4 bv = ((const float4*)b)[lane];
  float4 o;
  o.x = (v.x-mean)*rstd*gv.x + bv.x;
  o.y = (v.y-mean)*rstd*gv.y + bv.y;
  o.z = (v.z-mean)*rstd*gv.z + bv.z;
  o.w = (v.w-mean)*rstd*gv.w + bv.w;
  float4* op = (float4*)(out + (size_t)row*D_MODEL) + lane;
  if (ADD){ float4 hv = *op; o.x+=hv.x; o.y+=hv.y; o.z+=hv.z; o.w+=hv.w; }
  *op = o;
}

// ---------------- generic fp32 tiled GEMM (out/ff1/ff2 projections) ----------------
template<bool BIAS, bool RESID, bool ACCUM, bool ASCALE>
__global__ __launch_bounds__(256) void gemm_tiled(
    const float* __restrict__ A, const float* __restrict__ Bm,
    const float* __restrict__ bias, const float* __restrict__ resid,
    const float* __restrict__ asc, float* __restrict__ C,
    int M, int N, int K)
{
  __shared__ __align__(16) float As[16][68];
  __shared__ __align__(16) float Bs[16][68];
  const int t  = threadIdx.x;
  const int m0 = blockIdx.y*64, n0 = blockIdx.x*64;
  const int am = t>>2,  ak = (t&3)<<2;
  const int bk = t>>4,  bn = (t&15)<<2;
  const int rg = (t>>4)<<2, cg = (t&15)<<2;
  const float* Ap = A  + (size_t)(m0+am)*K + ak;
  const float* Bp = Bm + (size_t)bk*N + n0 + bn;
  const float* vp = ASCALE ? (asc + (size_t)((m0+am)>>10)*K + ak) : nullptr;
  float acc[4][4] = {};
  for (int k0 = 0; k0 < K; k0 += 16){
    float4 a4 = *(const float4*)(Ap + k0);
    float4 b4 = *(const float4*)(Bp + (size_t)k0*N);
    if (ASCALE){
      a4.x *= vp[k0+0]; a4.y *= vp[k0+1]; a4.z *= vp[k0+2]; a4.w *= vp[k0+3];
    }
    As[ak+0][am]=a4.x; As[ak+1][am]=a4.y; As[ak+2][am]=a4.z; As[ak+3][am]=a4.w;
    *(float4*)&Bs[bk][bn] = b4;
    __syncthreads();
    #pragma unroll
    for (int kk=0; kk<16; ++kk){
      float4 av = *(const float4*)&As[kk][rg];
      float4 bv = *(const float4*)&Bs[kk][cg];
      acc[0][0]=fmaf(av.x,bv.x,acc[0][0]); acc[0][1]=fmaf(av.x,bv.y,acc[0][1]);
      acc[0][2]=fmaf(av.x,bv.z,acc[0][2]); acc[0][3]=fmaf(av.x,bv.w,acc[0][3]);
      acc[1][0]=fmaf(av.y,bv.x,acc[1][0]); acc[1][1]=fmaf(av.y,bv.y,acc[1][1]);
      acc[1][2]=fmaf(av.y,bv.z,acc[1][2]); acc[1][3]=fmaf(av.y,bv.w,acc[1][3]);
      acc[2][0]=fmaf(av.z,bv.x,acc[2][0]); acc[2][1]=fmaf(av.z,bv.y,acc[2][1]);
      acc[2][2]=fmaf(av.z,bv.z,acc[2][2]); acc[2][3]=fmaf(av.z,bv.w,acc[2][3]);
      acc[3][0]=fmaf(av.w,bv.x,acc[3][0]); acc[3][1]=fmaf(av.w,bv.y,acc[3][1]);
      acc[3][2]=fmaf(av.w,bv.z,acc[3][2]); acc[3][3]=fmaf(av.w,bv.w,acc[3][3]);
    }
    __syncthreads();
  }
  float4 bb = make_float4(0.f,0.f,0.f,0.f);
  if (BIAS) bb = *(const float4*)(bias + n0 + cg);
  #pragma unroll
  for (int i=0;i<4;++i){
    size_t off = (size_t)(m0+rg+i)*N + n0 + cg;
    float4 c = make_float4(acc[i][0],acc[i][1],acc[i][2],acc[i][3]);
    if (BIAS){ c.x+=bb.x; c.y+=bb.y; c.z+=bb.z; c.w+=bb.w; }
    if (RESID){ float4 r=*(const float4*)(resid+off); c.x+=r.x; c.y+=r.y; c.z+=r.z; c.w+=r.w; }
    if (ACCUM){ float4 r=*(const float4*)(C+off);     c.x+=r.x; c.y+=r.y; c.z+=r.z; c.w+=r.w; }
    *(float4*)(C+off) = c;
  }
}

// ---------------- QKV GEMM: fp32 compute, bf16 epilogue ----------------
// Writes Q,K as qkbf[qk][bh][l][32] (row-major per head) and V transposed
// as vT[bh][dim32][l] for MFMA B-fragment-friendly global reads.
__global__ __launch_bounds__(256) void gemm_qkv(
    const float* __restrict__ A, const float* __restrict__ Bm,
    const float* __restrict__ bias, short* __restrict__ qkbf,
    short* __restrict__ vTb)
{
  __shared__ __align__(16) float As[16][68];
  __shared__ __align__(16) float Bs[16][68];
  const int t  = threadIdx.x;
  const int m0 = blockIdx.y*64, n0 = blockIdx.x*64;
  const int am = t>>2,  ak = (t&3)<<2;
  const int bk = t>>4,  bn = (t&15)<<2;
  const int rg = (t>>4)<<2, cg = (t&15)<<2;
  const float* Ap = A  + (size_t)(m0+am)*256 + ak;
  const float* Bp = Bm + (size_t)bk*768 + n0 + bn;
  float acc[4][4] = {};
  for (int k0 = 0; k0 < 256; k0 += 16){
    float4 a4 = *(const float4*)(Ap + k0);
    float4 b4 = *(const float4*)(Bp + (size_t)k0*768);
    As[ak+0][am]=a4.x; As[ak+1][am]=a4.y; As[ak+2][am]=a4.z; As[ak+3][am]=a4.w;
    *(float4*)&Bs[bk][bn] = b4;
    __syncthreads();
    #pragma unroll
    for (int kk=0; kk<16; ++kk){
      float4 av = *(const float4*)&As[kk][rg];
      float4 bv = *(const float4*)&Bs[kk][cg];
      acc[0][0]=fmaf(av.x,bv.x,acc[0][0]); acc[0][1]=fmaf(av.x,bv.y,acc[0][1]);
      acc[0][2]=fmaf(av.x,bv.z,acc[0][2]); acc[0][3]=fmaf(av.x,bv.w,acc[0][3]);
      acc[1][0]=fmaf(av.y,bv.x,acc[1][0]); acc[1][1]=fmaf(av.y,bv.y,acc[1][1]);
      acc[1][2]=fmaf(av.y,bv.z,acc[1][2]); acc[1][3]=fmaf(av.y,bv.w,acc[1][3]);
      acc[2][0]=fmaf(av.z,bv.x,acc[2][0]); acc[2][1]=fmaf(av.z,bv.y,acc[2][1]);
      acc[2][2]=fmaf(av.z,bv.z,acc[2][2]); acc[2][3]=fmaf(av.z,bv.w,acc[2][3]);
      acc[3][0]=fmaf(av.w,bv.x,acc[3][0]); acc[3][1]=fmaf(av.w,bv.y,acc[3][1]);
      acc[3][2]=fmaf(av.w,bv.z,acc[3][2]); acc[3][3]=fmaf(av.w,bv.w,acc[3][3]);
    }
    __syncthreads();
  }
  const int c0 = n0 + cg;            // global qkv col (0..767); region uniform per block
  float4 bb = *(const float4*)(bias + c0);
  const int l0 = m0 + rg;
  if (c0 < 512){                     // Q or K
    int region = c0 >> 8;            // 0=Q, 1=K
    int hh = (c0 >> 5) & 7, d0 = c0 & 31;
    #pragma unroll
    for (int i=0;i<4;++i){
      int lg = l0 + i;
      size_t base = (((size_t)(region*64 + (lg>>10)*8 + hh))*1024 + (lg & 1023))*32 + d0;
      short4 s4;
      s4.x = f2bf(acc[i][0]+bb.x); s4.y = f2bf(acc[i][1]+bb.y);
      s4.z = f2bf(acc[i][2]+bb.z); s4.w = f2bf(acc[i][3]+bb.w);
      *(short4*)(qkbf + base) = s4;
    }
  } else {                           // V (transposed store)
    int dv0 = c0 - 512;
    int b = l0 >> 10, lloc = l0 & 1023;
    const float bjs[4] = {bb.x, bb.y, bb.z, bb.w};
    #pragma unroll
    for (int j=0;j<4;++j){
      int dv = dv0 + j, hh = dv>>5, d = dv&31;
      size_t base = (((size_t)(b*8 + hh))*32 + d)*1024 + lloc;
      short4 s4;
      s4.x = f2bf(acc[0][j]+bjs[j]); s4.y = f2bf(acc[1][j]+bjs[j]);
      s4.z = f2bf(acc[2][j]+bjs[j]); s4.w = f2bf(acc[3][j]+bjs[j]);
      *(short4*)(vTb + base) = s4;
    }
  }
}

// ---------------- MFMA ProbSparse attention ----------------
// Block = (bh, 16 q rows). 4 waves split the 1024 keys (256 each).
// QK^T via mfma_16x16x32_bf16 (K=32=dk, one MFMA/tile), scores fp32 in LDS
// (XOR-swizzled so C-writes are 2-way not 4-way), exact top-256 threshold via
// ballot+popcount binary search, fp32 softmax, normalized bf16 weights written
// back over the score rows, P@V via MFMA with V^T fragments from global (L2).
__global__ __launch_bounds__(256,2) void attn_mfma(
    const short* __restrict__ qkbf, const short* __restrict__ vT,
    float* __restrict__ obuf)
{
  __shared__ float scw[16*1024];   // 64 KB: scores fp32 -> weights bf16 -> O partials
  const int t = threadIdx.x, wv = t>>6, lane = t&63;
  const int r16 = lane&15, quad = lane>>4;
  const int bh = blockIdx.x >> 6, qt = blockIdx.x & 63;

  // A-frag (Q): lane holds Q[q=r16][d=quad*8..+7], loaded once
  bf16x8 aq = *(const bf16x8*)(qkbf + ((size_t)bh*1024 + qt*16 + r16)*32 + quad*8);
  const short* kb = qkbf + (size_t)(64 + bh)*1024*32;   // K block
  const int msw = (quad<<2) ^ ((quad&1)<<4);            // bank swizzle for this quad

  // ---- QK pass: 16 key-tiles per wave ----
  bf16x8 bk[16];
  #pragma unroll
  for (int tt=0; tt<16; ++tt){
    int key0 = wv*256 + tt*16;
    bk[tt] = *(const bf16x8*)(kb + (size_t)(key0 + r16)*32 + quad*8);
  }
  #pragma unroll
  for (int tt=0; tt<16; ++tt){
    f32x4 c = {0.f,0.f,0.f,0.f};
    c = __builtin_amdgcn_mfma_f32_16x16x32_bf16(aq, bk[tt], c, 0, 0, 0);
    int p = ((wv*256 + tt*16) + r16) ^ msw;   // swizzled storage position
    #pragma unroll
    for (int r=0;r<4;++r)
      scw[(quad*4 + r)*1024 + p] = c[r];
  }
  __syncthreads();

  // ---- selection + softmax: wave wv owns rows 4wv..4wv+3 ----
  const float scale = 0.17677669529663687f;  // 1/sqrt(32)
  for (int rr=0; rr<4; ++rr){
    int row = wv*4 + rr;
    int ms = ((row>>2)<<2) ^ (((row>>2)&1)<<4);  // swizzle used when row was written
    float sc[16]; unsigned key[16];
    #pragma unroll
    for (int i=0;i<16;++i){
      sc[i] = scw[row*1024 + i*64 + lane];       // key index = (i*64+lane)^ms
      unsigned u = __float_as_uint(sc[i]);
      key[i] = (u & 0x80000000u) ? ~u : (u | 0x80000000u);
    }
    // exact 256th-largest key: count via ballot+popcount (SALU absorbs half)
    unsigned long long lo=0ULL, hi=0x100000000ULL;
    while (hi - lo > 1ULL){
      unsigned m32 = (unsigned)((lo+hi)>>1);
      int cnt = 0;
      #pragma unroll
      for (int i=0;i<16;++i)
        cnt += (int)__popcll(__ballot(key[i] >= m32));
      if (cnt >= TOPK) lo = (lo+hi)>>1; else hi = (lo+hi)>>1;
    }
    const unsigned thr = (unsigned)lo;
    float mx = sc[0];
    #pragma unroll
    for (int i=1;i<16;++i) mx = fmaxf(mx, sc[i]);
    mx = wmax(mx);
    float sum = 0.f, wvv[16];
    #pragma unroll
    for (int i=0;i<16;++i){
      float e = (key[i] >= thr) ? expf((sc[i]-mx)*scale) : 0.f;
      wvv[i] = e; sum += e;
    }
    sum = wsum(sum);
    const float inv = 1.f/sum;
    short* wrow = (short*)(scw + row*1024);      // weights alias row's own space
    #pragma unroll
    for (int i=0;i<16;++i)
      wrow[(i*64 + lane) ^ ms] = f2bf(wvv[i]*inv);   // store at TRUE key position
  }
  __syncthreads();

  // ---- PV pass: wave wv covers keys wv*256..+255; O partial [16q x 32d] ----
  const short* vb = vT + (size_t)bh*32*1024;
  bf16x8 bv[16];
  #pragma unroll
  for (int tt=0; tt<8; ++tt){
    int k0 = wv*256 + tt*32;
    #pragma unroll
    for (int n=0;n<2;++n)
      bv[tt*2+n] = *(const bf16x8*)(vb + (size_t)(n*16 + r16)*1024 + k0 + quad*8);
  }
  f32x4 oa0 = {0.f,0.f,0.f,0.f}, oa1 = {0.f,0.f,0.f,0.f};
  #pragma unroll
  for (int tt=0; tt<8; ++tt){
    int k0 = wv*256 + tt*32;
    bf16x8 af = *(const bf16x8*)((const short*)(scw + r16*1024) + k0 + quad*8);
    oa0 = __builtin_amdgcn_mfma_f32_16x16x32_bf16(af, bv[tt*2+0], oa0, 0, 0, 0);
    oa1 = __builtin_amdgcn_mfma_f32_16x16x32_bf16(af, bv[tt*2+1], oa1, 0, 0, 0);
  }
  __syncthreads();               // all weight reads done; scw reusable
  float* po = scw;               // [wave][16q][32d] partials (8 KB)
  #pragma unroll
  for (int r=0;r<4;++r){
    po[wv*512 + (quad*4+r)*32 +      r16] = oa0[r];
    po[wv*512 + (quad*4+r)*32 + 16 + r16] = oa1[r];
  }
  __syncthreads();
  int e = t*2;
  float v0 = po[e]   + po[512+e]   + po[1024+e]   + po[1536+e];
  float v1 = po[e+1] + po[512+e+1] + po[1024+e+1] + po[1536+e+1];
  int q = e>>5, d = e&31;
  int b = bh>>3, hh = bh&7;
  size_t off = ((size_t)(b*1024 + qt*16 + q))*256 + hh*32 + d;
  obuf[off]   = v0;
  obuf[off+1] = v1;
}

// ---------------- Volatilite vol: std over L per (b, ff-col) ----------------
__global__ __launch_bounds__(256) void vol_kernel(
    const float* __restrict__ f, float* __restrict__ vol)
{
  int b  = blockIdx.x >> 4, cb = blockIdx.x & 15;
  int cl = threadIdx.x & 63;
  int col = cb*64 + cl;
  int sl  = threadIdx.x >> 6;
  const float* fb = f + (size_t)b*L_*DFF + col;
  float s = 0.f, sq = 0.f;
  for (int l = sl*256; l < sl*256+256; ++l){
    float v = fb[(size_t)l*DFF];
    s += v; sq += v*v;
  }
  __shared__ float ps[4][64], pq[4][64];
  ps[sl][cl] = s; pq[sl][cl] = sq;
  __syncthreads();
  if (threadIdx.x < 64){
    float st = ps[0][cl]+ps[1][cl]+ps[2][cl]+ps[3][cl];
    float qt = pq[0][cl]+pq[1][cl]+pq[2][cl]+pq[3][cl];
    float mean = st*(1.f/L_);
    float var  = qt*(1.f/L_) - mean*mean;
    vol[(size_t)b*DFF + col] = sqrtf(fmaxf(var, 0.f));
  }
}

// ---------------- launch ----------------
extern "C" void kernel_launch(void* const* d_in, const int* in_sizes, int n_in,
                              void* d_out, int out_size, void* d_ws, size_t ws_size,
                              hipStream_t stream) {
  const float* x     = (const float*)d_in[0];
  const float* in_w  = (const float*)d_in[1];
  const float* in_b  = (const float*)d_in[2];
  const float* ln1_g = (const float*)d_in[3];
  const float* ln1_b = (const float*)d_in[4];
  const float* qkv_w = (const float*)d_in[5];
  const float* qkv_b = (const float*)d_in[6];
  const float* out_w = (const float*)d_in[7];
  const float* out_b = (const float*)d_in[8];
  const float* lna_g = (const float*)d_in[9];
  const float* lna_b = (const float*)d_in[10];
  const float* ln2_g = (const float*)d_in[11];
  const float* ln2_b = (const float*)d_in[12];
  const float* ff1_w = (const float*)d_in[13];
  const float* ff1_b = (const float*)d_in[14];
  const float* ff2_w = (const float*)d_in[15];
  const float* ff2_b = (const float*)d_in[16];
  const float* lnf_g = (const float*)d_in[17];
  const float* lnf_b = (const float*)d_in[18];
  float* out = (float*)d_out;

  // ws layout (48 MB + 4 KB):
  //  h @0 (8M) | s2 @8M (8M) | qkbf @16M (8M bf16) | vT @24M (4M bf16)
  //  ob @28M (8M) | tb @36M (8M) | f @16M..48M (aliases qkbf/vT/ob/tb, all
  //  dead before ff1 writes f) | vol @48M (32K)
  char* ws = (char*)d_ws;
  float* h    = (float*)(ws);
  float* s2   = (float*)(ws + (size_t)( 8<<20));
  short* qkbf = (short*)(ws + (size_t)(16<<20));
  short* vTb  = (short*)(ws + (size_t)(24<<20));
  float* ob   = (float*)(ws + (size_t)(28<<20));
  float* tb   = (float*)(ws + (size_t)(36<<20));
  float* f    = (float*)(ws + (size_t)(16<<20));
  float* vol  = (float*)(ws + (size_t)(48<<20));

  embed_kernel<<<NR*64/256, 256, 0, stream>>>(x, in_w, in_b, h);

  for (int layer = 0; layer < NLAYERS; ++layer){
    // s2 = LN(h)
    ln_kernel<false><<<NR/4, 256, 0, stream>>>(h, ln1_g, ln1_b, s2);
    // qkv = s2 @ qkv_w + qkv_b  -> bf16 Q,K (row-major) + bf16 V^T
    {
      dim3 g(768/64, NR/64);
      gemm_qkv<<<g, 256, 0, stream>>>(s2, qkv_w, qkv_b, qkbf, vTb);
    }
    // ob = ProbSparse attention (MFMA)
    attn_mfma<<<64*64, 256, 0, stream>>>(qkbf, vTb, ob);
    // tb = ob @ out_w + out_b + s2
    {
      dim3 g(256/64, NR/64);
      gemm_tiled<true,true,false,false><<<g, 256, 0, stream>>>(
          ob, out_w, out_b, s2, nullptr, tb, NR, D_MODEL, D_MODEL);
    }
    // h += LN(tb)
    ln_kernel<true><<<NR/4, 256, 0, stream>>>(tb, lna_g, lna_b, h);
    // s2 = LN(h)
    ln_kernel<false><<<NR/4, 256, 0, stream>>>(h, ln2_g, ln2_b, s2);
    // f = s2 @ ff1_w + ff1_b
    {
      dim3 g(1024/64, NR/64);
      gemm_tiled<true,false,false,false><<<g, 256, 0, stream>>>(
          s2, ff1_w, ff1_b, nullptr, nullptr, f, NR, DFF, D_MODEL);
    }
    // vol = std over L of f
    vol_kernel<<<B_*16, 256, 0, stream>>>(f, vol);
    // h += (f * vol) @ ff2_w + ff2_b
    {
      dim3 g(256/64, NR/64);
      gemm_tiled<true,false,true,true><<<g, 256, 0, stream>>>(
          f, ff2_w, ff2_b, nullptr, vol, h, NR, D_MODEL, DFF);
    }
  }
  // out = LN(h)
  ln_kernel<false><<<NR/4, 256, 0, stream>>>(h, lnf_g, lnf_b, out);
}

// Round 3
// 1361.527 us; speedup vs baseline: 4.4959x; 2.4867x over previous
//
#include <hip/hip_runtime.h>
#include <math.h>

#define D_MODEL 256
#define NH 8
#define DFF 1024
#define NLAYERS 6
#define B_ 8
#define L_ 1024
#define NR (B_*L_)          // 8192 rows
#define TOPK 256            // L/4
#define LNEPS 1e-5f

typedef __attribute__((ext_vector_type(8))) short bf16x8;
typedef __attribute__((ext_vector_type(4))) float f32x4;

// ---------------- helpers ----------------
__device__ __forceinline__ float wsum(float v){
  #pragma unroll
  for(int o=32;o>0;o>>=1) v += __shfl_xor(v,o,64);
  return v;
}
__device__ __forceinline__ float wmax(float v){
  #pragma unroll
  for(int o=32;o>0;o>>=1) v = fmaxf(v,__shfl_xor(v,o,64));
  return v;
}
__device__ __forceinline__ short f2bf(float x){
  unsigned u = __float_as_uint(x);
  u += 0x7fffu + ((u>>16)&1u);   // RNE (finite inputs only)
  return (short)(u>>16);
}
__device__ __forceinline__ float bf2f(short s){
  return __uint_as_float(((unsigned)(unsigned short)s)<<16);
}
// async global->LDS, 16B per lane (LDS dest must be uniform base + lane*16)
__device__ __forceinline__ void g2l(const short* g, short* l){
  __builtin_amdgcn_global_load_lds(
      (const __attribute__((address_space(1))) unsigned int*)g,
      (__attribute__((address_space(3))) unsigned int*)l,
      16, 0, 0);
}

// ---------------- embed: h = x@in_w + in_b + pe ----------------
__global__ __launch_bounds__(256) void embed_kernel(
    const float* __restrict__ x, const float* __restrict__ in_w,
    const float* __restrict__ in_b, float* __restrict__ h)
{
  int tid = blockIdx.x*256 + threadIdx.x;
  int n  = tid >> 6;
  int d0 = (tid & 63) << 2;
  int l  = n & (L_-1);
  float x0 = x[2*n], x1 = x[2*n+1];
  const float kf = -0.07195578415606394f;   // -ln(10000)/128
  float pe[4];
  #pragma unroll
  for(int ii=0; ii<2; ++ii){
    int i = (d0>>1) + ii;
    float dv  = expf((float)i * kf);
    float ang = (float)l * dv;
    pe[2*ii]   = sinf(ang);
    pe[2*ii+1] = cosf(ang);
  }
  float4 w0 = *(const float4*)(in_w + d0);
  float4 w1 = *(const float4*)(in_w + D_MODEL + d0);
  float4 bb = *(const float4*)(in_b + d0);
  float4 o;
  o.x = x0*w0.x + x1*w1.x + bb.x + pe[0];
  o.y = x0*w0.y + x1*w1.y + bb.y + pe[1];
  o.z = x0*w0.z + x1*w1.z + bb.z + pe[2];
  o.w = x0*w0.w + x1*w1.w + bb.w + pe[3];
  *(float4*)(h + (size_t)n*D_MODEL + d0) = o;
}

// ---------------- weight convert+transpose: WT[n][k] = bf16(W[k][n]) ----------------
__global__ __launch_bounds__(256) void wcvt(
    const float* __restrict__ W, short* __restrict__ WT, int N, int kshift)
{
  int idx = blockIdx.x*256 + threadIdx.x;
  int K = 1<<kshift;
  if (idx >= N*K) return;
  int n = idx >> kshift, k = idx & (K-1);
  WT[idx] = f2bf(W[(size_t)k*N + n]);
}

// ---------------- LayerNorm: wave per row ----------------
// OM: 0 = fp32 out, 1 = fp32 + bf16 out, 2 = bf16 out only, 3 = fp32 out += LN(in)
template<int OM>
__global__ __launch_bounds__(256) void ln_kernel(
    const float* __restrict__ in, const float* __restrict__ g,
    const float* __restrict__ b, float* __restrict__ out,
    short* __restrict__ outb)
{
  int wave = threadIdx.x >> 6, lane = threadIdx.x & 63;
  int row = blockIdx.x*4 + wave;
  float4 v = ((const float4*)(in + (size_t)row*D_MODEL))[lane];
  float s  = v.x+v.y+v.z+v.w;
  float sq = v.x*v.x+v.y*v.y+v.z*v.z+v.w*v.w;
  s = wsum(s); sq = wsum(sq);
  float mean = s*(1.f/D_MODEL);
  float var  = sq*(1.f/D_MODEL) - mean*mean;
  float rstd = 1.f/sqrtf(var + LNEPS);
  float4 gv = ((const float4*)g)[lane];
  float4 bv = ((const float4*)b)[lane];
  float4 o;
  o.x = (v.x-mean)*rstd*gv.x + bv.x;
  o.y = (v.y-mean)*rstd*gv.y + bv.y;
  o.z = (v.z-mean)*rstd*gv.z + bv.z;
  o.w = (v.w-mean)*rstd*gv.w + bv.w;
  if (OM == 0 || OM == 1){
    ((float4*)(out + (size_t)row*D_MODEL))[lane] = o;
  }
  if (OM == 3){
    float4* op = (float4*)(out + (size_t)row*D_MODEL) + lane;
    float4 hv = *op;
    o.x+=hv.x; o.y+=hv.y; o.z+=hv.z; o.w+=hv.w;
    *op = o;
  }
  if (OM == 1 || OM == 2){
    short4 s4; s4.x=f2bf(o.x); s4.y=f2bf(o.y); s4.z=f2bf(o.z); s4.w=f2bf(o.w);
    *(short4*)(outb + (size_t)row*D_MODEL + lane*4) = s4;
  }
}

// ---------------- bf16 MFMA GEMM: C[M x N] = A[M x K] @ BT[N x K]^T ----------------
// tile 128(M) x 64(N), BK=32, 256 thr = 4 waves, wave = 32x64 (2x4 16x16 tiles).
// MODE 0: qkv epilogue (Q/K row-major bf16 + V^T bf16)
// MODE 1: Cf = acc + bias + resid (fp32)
// MODE 2: Cb = bf16(acc + bias)
// MODE 3: Cf += acc + bias (fp32 accumulate into h)
template<int MODE>
__global__ __launch_bounds__(256) void mfma_gemm(
    const short* __restrict__ A, const short* __restrict__ BT,
    const float* __restrict__ bias, const float* __restrict__ resid,
    float* __restrict__ Cf, short* __restrict__ Cb, short* __restrict__ Vt,
    int N, int K)
{
  __shared__ __align__(16) short As[128*32];   // 8 KB [m][k]
  __shared__ __align__(16) short Bs[64*32];    // 4 KB [n][k]
  const int t = threadIdx.x, wv = t>>6, lane = t&63;
  const int r16 = lane&15, quad = lane>>4;
  const int m0 = blockIdx.y*128, n0 = blockIdx.x*64;
  const int ia0 = wv*128 + lane, ia1 = ia0 + 64;  // A chunks (512 of 16B)
  const int ib  = wv*64 + lane;                   // B chunks (256 of 16B)
  const short* Ab = A  + (size_t)m0*K;
  const short* Bb = BT + (size_t)n0*K;
  const f32x4 z = {0.f,0.f,0.f,0.f};
  f32x4 acc[2][4];
  #pragma unroll
  for (int i=0;i<2;++i)
    #pragma unroll
    for (int j=0;j<4;++j) acc[i][j] = z;

  for (int k0 = 0; k0 < K; k0 += 32){
    __syncthreads();
    g2l(Ab + (size_t)(ia0>>2)*K + k0 + (ia0&3)*8, As + ia0*8);
    g2l(Ab + (size_t)(ia1>>2)*K + k0 + (ia1&3)*8, As + ia1*8);
    g2l(Bb + (size_t)(ib>>2)*K  + k0 + (ib&3)*8,  Bs + ib*8);
    __syncthreads();
    bf16x8 af0 = *(const bf16x8*)(As + ((wv*32      + r16)*32 + quad*8));
    bf16x8 af1 = *(const bf16x8*)(As + ((wv*32 + 16 + r16)*32 + quad*8));
    bf16x8 bf[4];
    #pragma unroll
    for (int ct=0; ct<4; ++ct)
      bf[ct] = *(const bf16x8*)(Bs + ((ct*16 + r16)*32 + quad*8));
    #pragma unroll
    for (int ct=0; ct<4; ++ct){
      acc[0][ct] = __builtin_amdgcn_mfma_f32_16x16x32_bf16(af0, bf[ct], acc[0][ct], 0,0,0);
      acc[1][ct] = __builtin_amdgcn_mfma_f32_16x16x32_bf16(af1, bf[ct], acc[1][ct], 0,0,0);
    }
  }

  #pragma unroll
  for (int rt=0; rt<2; ++rt){
    const int mb = m0 + wv*32 + rt*16 + quad*4;
    #pragma unroll
    for (int ct=0; ct<4; ++ct){
      const int n = n0 + ct*16 + r16;
      const float bv = bias[n];
      if (MODE == 0){
        if (n < 512){                    // Q or K: qkbf[region*64+bh][l][d]
          int region = n>>8, hh = (n>>5)&7, d = n&31;
          #pragma unroll
          for (int r=0;r<4;++r){
            int l = mb + r;
            size_t base = (((size_t)(region*64 + (l>>10)*8 + hh))*1024 + (l&1023))*32 + d;
            Cb[base] = f2bf(acc[rt][ct][r] + bv);
          }
        } else {                         // V transposed: vT[bh][d][l]
          int dv = n - 512, hh = dv>>5, d = dv&31;
          int b = mb>>10, lloc = mb&1023;
          size_t base = (((size_t)(b*8 + hh))*32 + d)*1024 + lloc;
          short4 s4;
          s4.x = f2bf(acc[rt][ct][0] + bv); s4.y = f2bf(acc[rt][ct][1] + bv);
          s4.z = f2bf(acc[rt][ct][2] + bv); s4.w = f2bf(acc[rt][ct][3] + bv);
          *(short4*)(Vt + base) = s4;
        }
      } else {
        #pragma unroll
        for (int r=0;r<4;++r){
          size_t off = (size_t)(mb + r)*N + n;
          float c = acc[rt][ct][r] + bv;
          if (MODE == 1) Cf[off] = c + resid[off];
          if (MODE == 2) Cb[off] = f2bf(c);
          if (MODE == 3) Cf[off] += c;
        }
      }
    }
  }
}

// ---------------- MFMA ProbSparse attention (bf16 scores, 32 KB LDS) ----------------
// Block = (bh, 16 q rows); 4 waves split 1024 keys (256 each).
// Scores bf16 in LDS [row][pos], pos = key ^ ((row&7)<<3). Exact top-256 on
// 16-bit sortable keys (16-iter ballot binary search), fp32 softmax, bf16
// weights overwrite scores in place, PV via MFMA, bf16 output.
__global__ __launch_bounds__(256,4) void attn_mfma(
    const short* __restrict__ qkbf, const short* __restrict__ vT,
    short* __restrict__ ob)
{
  __shared__ __align__(16) short sc16[16*1024];   // 32 KB
  const int t = threadIdx.x, wv = t>>6, lane = t&63;
  const int r16 = lane&15, quad = lane>>4;
  const int bh = blockIdx.x >> 6, qt = blockIdx.x & 63;

  bf16x8 aq = *(const bf16x8*)(qkbf + ((size_t)bh*1024 + qt*16 + r16)*32 + quad*8);
  const short* kb = qkbf + (size_t)(64 + bh)*1024*32;

  // ---- QK: 16 key-tiles per wave ----
  bf16x8 bk[16];
  #pragma unroll
  for (int tt=0; tt<16; ++tt)
    bk[tt] = *(const bf16x8*)(kb + (size_t)(wv*256 + tt*16 + r16)*32 + quad*8);
  #pragma unroll
  for (int tt=0; tt<16; ++tt){
    f32x4 c = {0.f,0.f,0.f,0.f};
    c = __builtin_amdgcn_mfma_f32_16x16x32_bf16(aq, bk[tt], c, 0, 0, 0);
    int key = wv*256 + tt*16 + r16;
    #pragma unroll
    for (int r=0;r<4;++r){
      int row = quad*4 + r;
      sc16[row*1024 + (key ^ ((row&7)<<3))] = f2bf(c[r]);
    }
  }
  __syncthreads();

  // ---- selection + softmax: wave wv owns rows 4wv..4wv+3 ----
  const float SC2 = 0.25500529485087056f;   // (1/sqrt(32)) * log2(e)
  for (int rr=0; rr<4; ++rr){
    int row = wv*4 + rr;
    int s = (row&7)<<3;
    float scv[16]; int key[16];
    #pragma unroll
    for (int i=0;i<16;++i){
      short hsh = sc16[row*1024 + ((i*64+lane) ^ s)];
      scv[i] = bf2f(hsh);
      int u = (int)(unsigned short)hsh;
      key[i] = (u & 0x8000) ? (u ^ 0xFFFF) : (u | 0x8000);
    }
    int lo=0, hi=65536;
    while (hi - lo > 1){
      int mid = (lo+hi)>>1;
      int cnt = 0;
      #pragma unroll
      for (int i=0;i<16;++i)
        cnt += (int)__popcll(__ballot(key[i] >= mid));
      if (cnt >= TOPK) lo = mid; else hi = mid;
    }
    const int thr = lo;
    float mx = scv[0];
    #pragma unroll
    for (int i=1;i<16;++i) mx = fmaxf(mx, scv[i]);
    mx = wmax(mx);
    float sum = 0.f, w[16];
    #pragma unroll
    for (int i=0;i<16;++i){
      float e = (key[i] >= thr) ? exp2f((scv[i]-mx)*SC2) : 0.f;
      w[i] = e; sum += e;
    }
    sum = wsum(sum);
    const float inv = 1.f/sum;
    #pragma unroll
    for (int i=0;i<16;++i)
      sc16[row*1024 + ((i*64+lane) ^ s)] = f2bf(w[i]*inv);
  }
  __syncthreads();

  // ---- PV: wave wv covers keys wv*256..+255 ----
  const short* vb = vT + (size_t)bh*32*1024;
  bf16x8 bvv[16];
  #pragma unroll
  for (int tt=0; tt<8; ++tt){
    int k0 = wv*256 + tt*32;
    #pragma unroll
    for (int n=0;n<2;++n)
      bvv[tt*2+n] = *(const bf16x8*)(vb + (size_t)(n*16 + r16)*1024 + k0 + quad*8);
  }
  f32x4 oa0 = {0.f,0.f,0.f,0.f}, oa1 = {0.f,0.f,0.f,0.f};
  #pragma unroll
  for (int tt=0; tt<8; ++tt){
    int k0 = wv*256 + tt*32;
    bf16x8 af = *(const bf16x8*)(sc16 + r16*1024 + ((k0 + quad*8) ^ ((r16&7)<<3)));
    oa0 = __builtin_amdgcn_mfma_f32_16x16x32_bf16(af, bvv[tt*2+0], oa0, 0, 0, 0);
    oa1 = __builtin_amdgcn_mfma_f32_16x16x32_bf16(af, bvv[tt*2+1], oa1, 0, 0, 0);
  }
  __syncthreads();
  float* po = (float*)sc16;          // 8 KB partials [wave][16q][32d]
  #pragma unroll
  for (int r=0;r<4;++r){
    po[wv*512 + (quad*4+r)*32 +      r16] = oa0[r];
    po[wv*512 + (quad*4+r)*32 + 16 + r16] = oa1[r];
  }
  __syncthreads();
  int e = t*2;
  float v0 = po[e]   + po[512+e]   + po[1024+e]   + po[1536+e];
  float v1 = po[e+1] + po[512+e+1] + po[1024+e+1] + po[1536+e+1];
  int q = e>>5, d = e&31;
  int b = bh>>3, hh = bh&7;
  size_t off = ((size_t)(b*1024 + qt*16 + q))*256 + hh*32 + d;
  short2 s2o; s2o.x = f2bf(v0); s2o.y = f2bf(v1);
  *(short2*)(ob + off) = s2o;
}

// ---------------- Volatilite: f *= std_L(f), in place (bf16) ----------------
__global__ __launch_bounds__(512) void vol_scale(short* __restrict__ f)
{
  __shared__ float ps[8][64], pq[8][64], vs[64];
  int b = blockIdx.x >> 4, cb = blockIdx.x & 15;
  int cl = threadIdx.x & 63, sl = threadIdx.x >> 6;   // 8 waves x 128 L each
  int col = cb*64 + cl;
  short* fb = f + (size_t)b*L_*DFF + col;
  float s = 0.f, sq = 0.f;
  for (int l = sl*128; l < sl*128+128; ++l){
    float v = bf2f(fb[(size_t)l*DFF]);
    s += v; sq += v*v;
  }
  ps[sl][cl] = s; pq[sl][cl] = sq;
  __syncthreads();
  if (threadIdx.x < 64){
    float st=0.f, qt=0.f;
    #pragma unroll
    for (int i=0;i<8;++i){ st += ps[i][cl]; qt += pq[i][cl]; }
    float mean = st*(1.f/L_);
    float var  = qt*(1.f/L_) - mean*mean;
    vs[cl] = sqrtf(fmaxf(var, 0.f));
  }
  __syncthreads();
  float vv = vs[cl];
  for (int l = sl*128; l < sl*128+128; ++l){
    size_t o = (size_t)l*DFF;
    fb[o] = f2bf(bf2f(fb[o]) * vv);
  }
}

// ---------------- launch ----------------
extern "C" void kernel_launch(void* const* d_in, const int* in_sizes, int n_in,
                              void* d_out, int out_size, void* d_ws, size_t ws_size,
                              hipStream_t stream) {
  const float* x     = (const float*)d_in[0];
  const float* in_w  = (const float*)d_in[1];
  const float* in_b  = (const float*)d_in[2];
  const float* ln1_g = (const float*)d_in[3];
  const float* ln1_b = (const float*)d_in[4];
  const float* qkv_w = (const float*)d_in[5];
  const float* qkv_b = (const float*)d_in[6];
  const float* out_w = (const float*)d_in[7];
  const float* out_b = (const float*)d_in[8];
  const float* lna_g = (const float*)d_in[9];
  const float* lna_b = (const float*)d_in[10];
  const float* ln2_g = (const float*)d_in[11];
  const float* ln2_b = (const float*)d_in[12];
  const float* ff1_w = (const float*)d_in[13];
  const float* ff1_b = (const float*)d_in[14];
  const float* ff2_w = (const float*)d_in[15];
  const float* ff2_b = (const float*)d_in[16];
  const float* lnf_g = (const float*)d_in[17];
  const float* lnf_b = (const float*)d_in[18];
  float* out = (float*)d_out;

  // ws layout (~47 MB):
  //  h    @0     8M fp32
  //  s2   @8M    8M fp32
  //  s2b  @16M   4M bf16
  //  qkbf @20M   8M bf16   (aliased by f after attention)
  //  vTb  @28M   4M bf16   (aliased by f)
  //  ob_b @32M   4M bf16   (aliased by f)
  //  f    @20M  16M bf16   (alias: qkbf/vTb/ob_b dead at ff1 time)
  //  tb   @36M   8M fp32
  //  wT   @45M  ~1.6M bf16 (qkv 384K, out 128K, ff1 512K, ff2 512K)
  char* ws = (char*)d_ws;
  float* h     = (float*)(ws);
  float* s2    = (float*)(ws + (size_t)( 8<<20));
  short* s2b   = (short*)(ws + (size_t)(16<<20));
  short* qkbf  = (short*)(ws + (size_t)(20<<20));
  short* vTb   = (short*)(ws + (size_t)(28<<20));
  short* ob_b  = (short*)(ws + (size_t)(32<<20));
  short* f     = (short*)(ws + (size_t)(20<<20));
  float* tb    = (float*)(ws + (size_t)(36<<20));
  short* qkvwT = (short*)(ws + (size_t)(45<<20));
  short* outwT = (short*)(ws + (size_t)(45<<20) + 393216);
  short* ff1wT = (short*)(ws + (size_t)(45<<20) + 393216 + 131072);
  short* ff2wT = (short*)(ws + (size_t)(45<<20) + 393216 + 131072 + 524288);

  embed_kernel<<<NR*64/256, 256, 0, stream>>>(x, in_w, in_b, h);
  wcvt<<< 768, 256, 0, stream>>>(qkv_w, qkvwT,  768, 8);
  wcvt<<< 256, 256, 0, stream>>>(out_w, outwT,  256, 8);
  wcvt<<<1024, 256, 0, stream>>>(ff1_w, ff1wT, 1024, 8);
  wcvt<<<1024, 256, 0, stream>>>(ff2_w, ff2wT,  256, 10);

  for (int layer = 0; layer < NLAYERS; ++layer){
    // s2 = LN(h) (fp32 + bf16)
    ln_kernel<1><<<NR/4, 256, 0, stream>>>(h, ln1_g, ln1_b, s2, s2b);
    // qkv GEMM -> bf16 Q,K row-major + bf16 V^T
    {
      dim3 g(768/64, NR/128);
      mfma_gemm<0><<<g, 256, 0, stream>>>(s2b, qkvwT, qkv_b, nullptr,
                                          nullptr, qkbf, vTb, 768, 256);
    }
    // ProbSparse attention -> ob bf16
    attn_mfma<<<64*64, 256, 0, stream>>>(qkbf, vTb, ob_b);
    // tb = ob @ out_w + out_b + s2 (fp32)
    {
      dim3 g(256/64, NR/128);
      mfma_gemm<1><<<g, 256, 0, stream>>>(ob_b, outwT, out_b, s2,
                                          tb, nullptr, nullptr, 256, 256);
    }
    // h += LN(tb)
    ln_kernel<3><<<NR/4, 256, 0, stream>>>(tb, lna_g, lna_b, h, nullptr);
    // s2b = LN(h) (bf16 only)
    ln_kernel<2><<<NR/4, 256, 0, stream>>>(h, ln2_g, ln2_b, nullptr, s2b);
    // f = bf16(s2 @ ff1_w + ff1_b)
    {
      dim3 g(1024/64, NR/128);
      mfma_gemm<2><<<g, 256, 0, stream>>>(s2b, ff1wT, ff1_b, nullptr,
                                          nullptr, f, nullptr, 1024, 256);
    }
    // f *= std_L(f) in place
    vol_scale<<<B_*16, 512, 0, stream>>>(f);
    // h += f @ ff2_w + ff2_b
    {
      dim3 g(256/64, NR/128);
      mfma_gemm<3><<<g, 256, 0, stream>>>(f, ff2wT, ff2_b, nullptr,
                                          h, nullptr, nullptr, 256, 1024);
    }
  }
  // out = LN(h)
  ln_kernel<0><<<NR/4, 256, 0, stream>>>(h, lnf_g, lnf_b, out, nullptr);
}

// Round 4
// 1281.798 us; speedup vs baseline: 4.7756x; 1.0622x over previous
//
#include <hip/hip_runtime.h>
#include <math.h>

#define D_MODEL 256
#define NH 8
#define DFF 1024
#define NLAYERS 6
#define B_ 8
#define L_ 1024
#define NR (B_*L_)          // 8192 rows
#define TOPK 256            // L/4
#define LNEPS 1e-5f

typedef __attribute__((ext_vector_type(8))) short bf16x8;
typedef __attribute__((ext_vector_type(4))) float f32x4;

// ---------------- helpers ----------------
__device__ __forceinline__ float wsum(float v){
  #pragma unroll
  for(int o=32;o>0;o>>=1) v += __shfl_xor(v,o,64);
  return v;
}
__device__ __forceinline__ short f2bf(float x){
  unsigned u = __float_as_uint(x);
  u += 0x7fffu + ((u>>16)&1u);   // RNE (finite inputs only)
  return (short)(u>>16);
}
__device__ __forceinline__ float bf2f(short s){
  return __uint_as_float(((unsigned)(unsigned short)s)<<16);
}
// bf16 raw bits -> 16-bit sortable key (order-isomorphic to float value)
__device__ __forceinline__ int sortkey(unsigned u){
  return (u & 0x8000u) ? (int)(u ^ 0xFFFFu) : (int)(u | 0x8000u);
}
// sortable key -> float value
__device__ __forceinline__ float kinvf(int k){
  unsigned u = (k & 0x8000) ? ((unsigned)k ^ 0x8000u) : ((unsigned)k ^ 0xFFFFu);
  return __uint_as_float(u << 16);
}
// async global->LDS, 16B per lane
__device__ __forceinline__ void g2l(const short* g, short* l){
  __builtin_amdgcn_global_load_lds(
      (const __attribute__((address_space(1))) unsigned int*)g,
      (__attribute__((address_space(3))) unsigned int*)l,
      16, 0, 0);
}

// ---------------- embed: h = x@in_w + in_b + pe ----------------
__global__ __launch_bounds__(256) void embed_kernel(
    const float* __restrict__ x, const float* __restrict__ in_w,
    const float* __restrict__ in_b, float* __restrict__ h)
{
  int tid = blockIdx.x*256 + threadIdx.x;
  int n  = tid >> 6;
  int d0 = (tid & 63) << 2;
  int l  = n & (L_-1);
  float x0 = x[2*n], x1 = x[2*n+1];
  const float kf = -0.07195578415606394f;   // -ln(10000)/128
  float pe[4];
  #pragma unroll
  for(int ii=0; ii<2; ++ii){
    int i = (d0>>1) + ii;
    float dv  = expf((float)i * kf);
    float ang = (float)l * dv;
    pe[2*ii]   = sinf(ang);
    pe[2*ii+1] = cosf(ang);
  }
  float4 w0 = *(const float4*)(in_w + d0);
  float4 w1 = *(const float4*)(in_w + D_MODEL + d0);
  float4 bb = *(const float4*)(in_b + d0);
  float4 o;
  o.x = x0*w0.x + x1*w1.x + bb.x + pe[0];
  o.y = x0*w0.y + x1*w1.y + bb.y + pe[1];
  o.z = x0*w0.z + x1*w1.z + bb.z + pe[2];
  o.w = x0*w0.w + x1*w1.w + bb.w + pe[3];
  *(float4*)(h + (size_t)n*D_MODEL + d0) = o;
}

// ---------------- weight convert+transpose: WT[n][k] = bf16(W[k][n]) ----------------
__global__ __launch_bounds__(256) void wcvt(
    const float* __restrict__ W, short* __restrict__ WT, int N, int kshift)
{
  int idx = blockIdx.x*256 + threadIdx.x;
  int K = 1<<kshift;
  if (idx >= N*K) return;
  int n = idx >> kshift, k = idx & (K-1);
  WT[idx] = f2bf(W[(size_t)k*N + n]);
}

// ---------------- LayerNorm: wave per row ----------------
// OM: 0 = fp32 out, 2 = bf16 out only
template<int OM>
__global__ __launch_bounds__(256) void ln_kernel(
    const float* __restrict__ in, const float* __restrict__ g,
    const float* __restrict__ b, float* __restrict__ out,
    short* __restrict__ outb)
{
  int wave = threadIdx.x >> 6, lane = threadIdx.x & 63;
  int row = blockIdx.x*4 + wave;
  float4 v = ((const float4*)(in + (size_t)row*D_MODEL))[lane];
  float s  = v.x+v.y+v.z+v.w;
  float sq = v.x*v.x+v.y*v.y+v.z*v.z+v.w*v.w;
  s = wsum(s); sq = wsum(sq);
  float mean = s*(1.f/D_MODEL);
  float var  = sq*(1.f/D_MODEL) - mean*mean;
  float rstd = 1.f/sqrtf(var + LNEPS);
  float4 gv = ((const float4*)g)[lane];
  float4 bv = ((const float4*)b)[lane];
  float4 o;
  o.x = (v.x-mean)*rstd*gv.x + bv.x;
  o.y = (v.y-mean)*rstd*gv.y + bv.y;
  o.z = (v.z-mean)*rstd*gv.z + bv.z;
  o.w = (v.w-mean)*rstd*gv.w + bv.w;
  if (OM == 0){
    ((float4*)(out + (size_t)row*D_MODEL))[lane] = o;
  }
  if (OM == 2){
    short4 s4; s4.x=f2bf(o.x); s4.y=f2bf(o.y); s4.z=f2bf(o.z); s4.w=f2bf(o.w);
    *(short4*)(outb + (size_t)row*D_MODEL + lane*4) = s4;
  }
}

// ---------------- fused: h += LN_a(tb); s2b = bf16(LN_2(h)) ----------------
__global__ __launch_bounds__(256) void lnln_kernel(
    const float* __restrict__ tb,
    const float* __restrict__ ga, const float* __restrict__ ba,
    const float* __restrict__ g2, const float* __restrict__ b2,
    float* __restrict__ h, short* __restrict__ s2b)
{
  int wave = threadIdx.x >> 6, lane = threadIdx.x & 63;
  int row = blockIdx.x*4 + wave;
  float4 v = ((const float4*)(tb + (size_t)row*D_MODEL))[lane];
  float s  = v.x+v.y+v.z+v.w;
  float sq = v.x*v.x+v.y*v.y+v.z*v.z+v.w*v.w;
  s = wsum(s); sq = wsum(sq);
  float mean = s*(1.f/D_MODEL);
  float var  = sq*(1.f/D_MODEL) - mean*mean;
  float rstd = 1.f/sqrtf(var + LNEPS);
  float4 gv = ((const float4*)ga)[lane];
  float4 bv = ((const float4*)ba)[lane];
  float4* hp = (float4*)(h + (size_t)row*D_MODEL) + lane;
  float4 hv = *hp;
  float4 hn;
  hn.x = hv.x + (v.x-mean)*rstd*gv.x + bv.x;
  hn.y = hv.y + (v.y-mean)*rstd*gv.y + bv.y;
  hn.z = hv.z + (v.z-mean)*rstd*gv.z + bv.z;
  hn.w = hv.w + (v.w-mean)*rstd*gv.w + bv.w;
  *hp = hn;
  // second LN over hn
  float s2  = hn.x+hn.y+hn.z+hn.w;
  float sq2 = hn.x*hn.x+hn.y*hn.y+hn.z*hn.z+hn.w*hn.w;
  s2 = wsum(s2); sq2 = wsum(sq2);
  float m2 = s2*(1.f/D_MODEL);
  float v2 = sq2*(1.f/D_MODEL) - m2*m2;
  float r2 = 1.f/sqrtf(v2 + LNEPS);
  float4 g2v = ((const float4*)g2)[lane];
  float4 b2v = ((const float4*)b2)[lane];
  short4 s4;
  s4.x = f2bf((hn.x-m2)*r2*g2v.x + b2v.x);
  s4.y = f2bf((hn.y-m2)*r2*g2v.y + b2v.y);
  s4.z = f2bf((hn.z-m2)*r2*g2v.z + b2v.z);
  s4.w = f2bf((hn.w-m2)*r2*g2v.w + b2v.w);
  *(short4*)(s2b + (size_t)row*D_MODEL + lane*4) = s4;
}

// ---------------- bf16 MFMA GEMM: C[M x N] = A[M x K] @ BT[N x K]^T ----------------
// tile 128(M) x 64(N), BK=32, 256 thr = 4 waves.
// MODE 0: qkv epilogue (Q/K row-major bf16 + V^T bf16)
// MODE 1: Cf = acc + bias + bf2f(residb)    (fp32 out)
// MODE 2: Cb = bf16(acc + bias)
// MODE 3: Cf += acc + bias                  (fp32 accumulate into h)
template<int MODE>
__global__ __launch_bounds__(256) void mfma_gemm(
    const short* __restrict__ A, const short* __restrict__ BT,
    const float* __restrict__ bias, const short* __restrict__ residb,
    float* __restrict__ Cf, short* __restrict__ Cb, short* __restrict__ Vt,
    int N, int K)
{
  __shared__ __align__(16) short As[128*32];   // 8 KB [m][k]
  __shared__ __align__(16) short Bs[64*32];    // 4 KB [n][k]
  const int t = threadIdx.x, wv = t>>6, lane = t&63;
  const int r16 = lane&15, quad = lane>>4;
  const int m0 = blockIdx.y*128, n0 = blockIdx.x*64;
  const int ia0 = wv*128 + lane, ia1 = ia0 + 64;
  const int ib  = wv*64 + lane;
  const short* Ab = A  + (size_t)m0*K;
  const short* Bb = BT + (size_t)n0*K;
  const f32x4 z = {0.f,0.f,0.f,0.f};
  f32x4 acc[2][4];
  #pragma unroll
  for (int i=0;i<2;++i)
    #pragma unroll
    for (int j=0;j<4;++j) acc[i][j] = z;

  for (int k0 = 0; k0 < K; k0 += 32){
    __syncthreads();
    g2l(Ab + (size_t)(ia0>>2)*K + k0 + (ia0&3)*8, As + ia0*8);
    g2l(Ab + (size_t)(ia1>>2)*K + k0 + (ia1&3)*8, As + ia1*8);
    g2l(Bb + (size_t)(ib>>2)*K  + k0 + (ib&3)*8,  Bs + ib*8);
    __syncthreads();
    bf16x8 af0 = *(const bf16x8*)(As + ((wv*32      + r16)*32 + quad*8));
    bf16x8 af1 = *(const bf16x8*)(As + ((wv*32 + 16 + r16)*32 + quad*8));
    bf16x8 bf[4];
    #pragma unroll
    for (int ct=0; ct<4; ++ct)
      bf[ct] = *(const bf16x8*)(Bs + ((ct*16 + r16)*32 + quad*8));
    #pragma unroll
    for (int ct=0; ct<4; ++ct){
      acc[0][ct] = __builtin_amdgcn_mfma_f32_16x16x32_bf16(af0, bf[ct], acc[0][ct], 0,0,0);
      acc[1][ct] = __builtin_amdgcn_mfma_f32_16x16x32_bf16(af1, bf[ct], acc[1][ct], 0,0,0);
    }
  }

  #pragma unroll
  for (int rt=0; rt<2; ++rt){
    const int mb = m0 + wv*32 + rt*16 + quad*4;
    #pragma unroll
    for (int ct=0; ct<4; ++ct){
      const int n = n0 + ct*16 + r16;
      const float bv = bias[n];
      if (MODE == 0){
        if (n < 512){                    // Q or K: qkbf[region*64+bh][l][d]
          int region = n>>8, hh = (n>>5)&7, d = n&31;
          #pragma unroll
          for (int r=0;r<4;++r){
            int l = mb + r;
            size_t base = (((size_t)(region*64 + (l>>10)*8 + hh))*1024 + (l&1023))*32 + d;
            Cb[base] = f2bf(acc[rt][ct][r] + bv);
          }
        } else {                         // V transposed: vT[bh][d][l]
          int dv = n - 512, hh = dv>>5, d = dv&31;
          int b = mb>>10, lloc = mb&1023;
          size_t base = (((size_t)(b*8 + hh))*32 + d)*1024 + lloc;
          short4 s4;
          s4.x = f2bf(acc[rt][ct][0] + bv); s4.y = f2bf(acc[rt][ct][1] + bv);
          s4.z = f2bf(acc[rt][ct][2] + bv); s4.w = f2bf(acc[rt][ct][3] + bv);
          *(short4*)(Vt + base) = s4;
        }
      } else {
        #pragma unroll
        for (int r=0;r<4;++r){
          size_t off = (size_t)(mb + r)*N + n;
          float c = acc[rt][ct][r] + bv;
          if (MODE == 1) Cf[off] = c + bf2f(residb[off]);
          if (MODE == 2) Cb[off] = f2bf(c);
          if (MODE == 3) Cf[off] += c;
        }
      }
    }
  }
}

// ---------------- MFMA ProbSparse attention v2 ----------------
// Block = (bh, 16 q rows); XCD-swizzled so one head's K/V stays in one XCD's L2.
// Scores bf16 in LDS [row][key ^ s(row)], s(row)=((row>>2)&3)<<4 (bank spread).
// Selection: packed b32 score reads, 2-row-interleaved exact binary search on
// 16-bit sortable keys (ballot+popcount), fp32 softmax in float domain,
// UNNORMALIZED bf16 weights written back packed; 1/sum applied at output.
__global__ __launch_bounds__(256,4) void attn_mfma(
    const short* __restrict__ qkbf, const short* __restrict__ vT,
    short* __restrict__ ob)
{
  __shared__ __align__(16) short sc16[16*1024];   // 32 KB
  __shared__ float linv[16];
  const int t = threadIdx.x, wv = t>>6, lane = t&63;
  const int r16 = lane&15, quad = lane>>4;
  const int blk = blockIdx.x;
  const int bh = (blk & 7)*8 + ((blk>>3)&7);   // XCD-major: head pinned to XCD
  const int qt = blk >> 6;

  bf16x8 aq = *(const bf16x8*)(qkbf + ((size_t)bh*1024 + qt*16 + r16)*32 + quad*8);
  const short* kb = qkbf + (size_t)(64 + bh)*1024*32;

  // ---- QK: 16 key-tiles per wave; writes swizzled by quad (conflict-free) ----
  bf16x8 bk[16];
  #pragma unroll
  for (int tt=0; tt<16; ++tt)
    bk[tt] = *(const bf16x8*)(kb + (size_t)(wv*256 + tt*16 + r16)*32 + quad*8);
  #pragma unroll
  for (int tt=0; tt<16; ++tt){
    f32x4 c = {0.f,0.f,0.f,0.f};
    c = __builtin_amdgcn_mfma_f32_16x16x32_bf16(aq, bk[tt], c, 0, 0, 0);
    const int pos = wv*256 + ((tt ^ quad)<<4) + r16;   // key ^ (quad<<4)
    #pragma unroll
    for (int r=0;r<4;++r)
      sc16[(quad*4+r)*1024 + pos] = f2bf(c[r]);
  }
  __syncthreads();

  // ---- selection + softmax: wave wv owns rows 4wv..4wv+3 (shared swizzle) ----
  const float SC2 = 0.25500529485087056f;   // (1/sqrt(32)) * log2(e)
  const int sw = wv << 4;                   // s(row) for rows 4wv..4wv+3
  short* prow = sc16 + ((2*lane) ^ sw);
  for (int rp=0; rp<2; ++rp){
    const int ra = wv*4 + rp*2;
    short* pa = prow + ra*1024;
    short* pb = pa + 1024;
    unsigned wa[8], wb[8];
    #pragma unroll
    for (int i=0;i<8;++i){
      wa[i] = *(const unsigned*)(pa + i*128);
      wb[i] = *(const unsigned*)(pb + i*128);
    }
    int ka[16], kb2[16];
    #pragma unroll
    for (int i=0;i<8;++i){
      ka[2*i]    = sortkey(wa[i] & 0xFFFFu);
      ka[2*i+1]  = sortkey(wa[i] >> 16);
      kb2[2*i]   = sortkey(wb[i] & 0xFFFFu);
      kb2[2*i+1] = sortkey(wb[i] >> 16);
    }
    int mxa = ka[0], mxb = kb2[0];
    #pragma unroll
    for (int i=1;i<16;++i){
      mxa = (ka[i]  > mxa) ? ka[i]  : mxa;
      mxb = (kb2[i] > mxb) ? kb2[i] : mxb;
    }
    #pragma unroll
    for (int o=32;o>0;o>>=1){
      int sa = __shfl_xor(mxa, o, 64); mxa = (sa > mxa) ? sa : mxa;
      int sb = __shfl_xor(mxb, o, 64); mxb = (sb > mxb) ? sb : mxb;
    }
    // two interleaved exact binary searches (independent chains)
    int loA=0, hiA=mxa+1, loB=0, hiB=mxb+1;
    while (hiA-loA > 1 || hiB-loB > 1){
      int midA = (loA+hiA)>>1, midB = (loB+hiB)>>1;
      int cA=0, cB=0;
      #pragma unroll
      for (int i=0;i<16;++i){
        cA += (int)__popcll(__ballot(ka[i]  >= midA));
        cB += (int)__popcll(__ballot(kb2[i] >= midB));
      }
      if (cA >= TOPK) loA = midA; else hiA = midA;
      if (cB >= TOPK) loB = midB; else hiB = midB;
    }
    const float thrA = kinvf(loA), thrB = kinvf(loB);
    const float nmA = -kinvf(mxa)*SC2, nmB = -kinvf(mxb)*SC2;
    float suma = 0.f, sumb = 0.f;
    unsigned pka[8], pkb[8];
    #pragma unroll
    for (int i=0;i<8;++i){
      float a0 = __uint_as_float(wa[i] << 16);
      float a1 = __uint_as_float(wa[i] & 0xFFFF0000u);
      float b0 = __uint_as_float(wb[i] << 16);
      float b1 = __uint_as_float(wb[i] & 0xFFFF0000u);
      float ea0 = (a0 >= thrA) ? exp2f(fmaf(a0, SC2, nmA)) : 0.f;
      float ea1 = (a1 >= thrA) ? exp2f(fmaf(a1, SC2, nmA)) : 0.f;
      float eb0 = (b0 >= thrB) ? exp2f(fmaf(b0, SC2, nmB)) : 0.f;
      float eb1 = (b1 >= thrB) ? exp2f(fmaf(b1, SC2, nmB)) : 0.f;
      suma += ea0 + ea1; sumb += eb0 + eb1;
      pka[i] = (unsigned)(unsigned short)f2bf(ea0) | ((unsigned)(unsigned short)f2bf(ea1) << 16);
      pkb[i] = (unsigned)(unsigned short)f2bf(eb0) | ((unsigned)(unsigned short)f2bf(eb1) << 16);
    }
    suma = wsum(suma); sumb = wsum(sumb);
    if (lane == 0){ linv[ra] = 1.f/suma; linv[ra+1] = 1.f/sumb; }
    #pragma unroll
    for (int i=0;i<8;++i){
      *(unsigned*)(pa + i*128) = pka[i];
      *(unsigned*)(pb + i*128) = pkb[i];
    }
  }
  __syncthreads();

  // ---- PV: wave wv covers keys wv*256..+255 ----
  const short* vb = vT + (size_t)bh*32*1024;
  bf16x8 bvv[16];
  #pragma unroll
  for (int tt=0; tt<8; ++tt){
    int k0 = wv*256 + tt*32;
    #pragma unroll
    for (int n=0;n<2;++n)
      bvv[tt*2+n] = *(const bf16x8*)(vb + (size_t)(n*16 + r16)*1024 + k0 + quad*8);
  }
  const int sA = ((r16>>2)&3) << 4;    // s(row=r16)
  f32x4 oa0 = {0.f,0.f,0.f,0.f}, oa1 = {0.f,0.f,0.f,0.f};
  #pragma unroll
  for (int tt=0; tt<8; ++tt){
    int k0 = wv*256 + tt*32;
    bf16x8 af = *(const bf16x8*)(sc16 + r16*1024 + ((k0 + quad*8) ^ sA));
    oa0 = __builtin_amdgcn_mfma_f32_16x16x32_bf16(af, bvv[tt*2+0], oa0, 0, 0, 0);
    oa1 = __builtin_amdgcn_mfma_f32_16x16x32_bf16(af, bvv[tt*2+1], oa1, 0, 0, 0);
  }
  __syncthreads();
  float* po = (float*)sc16;          // 8 KB partials [wave][16q][32d]
  #pragma unroll
  for (int r=0;r<4;++r){
    po[wv*512 + (quad*4+r)*32 +      r16] = oa0[r];
    po[wv*512 + (quad*4+r)*32 + 16 + r16] = oa1[r];
  }
  __syncthreads();
  int e = t*2;
  float v0 = po[e]   + po[512+e]   + po[1024+e]   + po[1536+e];
  float v1 = po[e+1] + po[512+e+1] + po[1024+e+1] + po[1536+e+1];
  int q = e>>5, d = e&31;
  const float inv = linv[q];
  int b = bh>>3, hh = bh&7;
  size_t off = ((size_t)(b*1024 + qt*16 + q))*256 + hh*32 + d;
  short2 s2o; s2o.x = f2bf(v0*inv); s2o.y = f2bf(v1*inv);
  *(short2*)(ob + off) = s2o;
}

// ---------------- Volatilite: f *= std_L(f), in place (bf16) ----------------
__global__ __launch_bounds__(512) void vol_scale(short* __restrict__ f)
{
  __shared__ float ps[8][64], pq[8][64], vs[64];
  int b = blockIdx.x >> 4, cb = blockIdx.x & 15;
  int cl = threadIdx.x & 63, sl = threadIdx.x >> 6;   // 8 waves x 128 L each
  int col = cb*64 + cl;
  short* fb = f + (size_t)b*L_*DFF + col;
  float s = 0.f, sq = 0.f;
  for (int l = sl*128; l < sl*128+128; ++l){
    float v = bf2f(fb[(size_t)l*DFF]);
    s += v; sq += v*v;
  }
  ps[sl][cl] = s; pq[sl][cl] = sq;
  __syncthreads();
  if (threadIdx.x < 64){
    float st=0.f, qt=0.f;
    #pragma unroll
    for (int i=0;i<8;++i){ st += ps[i][cl]; qt += pq[i][cl]; }
    float mean = st*(1.f/L_);
    float var  = qt*(1.f/L_) - mean*mean;
    vs[cl] = sqrtf(fmaxf(var, 0.f));
  }
  __syncthreads();
  float vv = vs[cl];
  for (int l = sl*128; l < sl*128+128; ++l){
    size_t o = (size_t)l*DFF;
    fb[o] = f2bf(bf2f(fb[o]) * vv);
  }
}

// ---------------- launch ----------------
extern "C" void kernel_launch(void* const* d_in, const int* in_sizes, int n_in,
                              void* d_out, int out_size, void* d_ws, size_t ws_size,
                              hipStream_t stream) {
  const float* x     = (const float*)d_in[0];
  const float* in_w  = (const float*)d_in[1];
  const float* in_b  = (const float*)d_in[2];
  const float* ln1_g = (const float*)d_in[3];
  const float* ln1_b = (const float*)d_in[4];
  const float* qkv_w = (const float*)d_in[5];
  const float* qkv_b = (const float*)d_in[6];
  const float* out_w = (const float*)d_in[7];
  const float* out_b = (const float*)d_in[8];
  const float* lna_g = (const float*)d_in[9];
  const float* lna_b = (const float*)d_in[10];
  const float* ln2_g = (const float*)d_in[11];
  const float* ln2_b = (const float*)d_in[12];
  const float* ff1_w = (const float*)d_in[13];
  const float* ff1_b = (const float*)d_in[14];
  const float* ff2_w = (const float*)d_in[15];
  const float* ff2_b = (const float*)d_in[16];
  const float* lnf_g = (const float*)d_in[17];
  const float* lnf_b = (const float*)d_in[18];
  float* out = (float*)d_out;

  // ws layout (~37.6 MB):
  //  h @0 8M | s2b @8M 4M | qkbf @12M 8M | vTb @20M 4M | ob_b @24M 4M
  //  f @12M 16M (aliases qkbf/vTb/ob_b — dead at ff1 time) | tb @28M 8M
  //  weights @36M: qkv 384K + out 128K + ff1 512K + ff2 512K
  char* ws = (char*)d_ws;
  float* h     = (float*)(ws);
  short* s2b   = (short*)(ws + (size_t)( 8<<20));
  short* qkbf  = (short*)(ws + (size_t)(12<<20));
  short* vTb   = (short*)(ws + (size_t)(20<<20));
  short* ob_b  = (short*)(ws + (size_t)(24<<20));
  short* f     = (short*)(ws + (size_t)(12<<20));
  float* tb    = (float*)(ws + (size_t)(28<<20));
  short* qkvwT = (short*)(ws + (size_t)(36<<20));
  short* outwT = (short*)(ws + (size_t)(36<<20) + 393216);
  short* ff1wT = (short*)(ws + (size_t)(36<<20) + 393216 + 131072);
  short* ff2wT = (short*)(ws + (size_t)(36<<20) + 393216 + 131072 + 524288);

  embed_kernel<<<NR*64/256, 256, 0, stream>>>(x, in_w, in_b, h);
  wcvt<<< 768, 256, 0, stream>>>(qkv_w, qkvwT,  768, 8);
  wcvt<<< 256, 256, 0, stream>>>(out_w, outwT,  256, 8);
  wcvt<<<1024, 256, 0, stream>>>(ff1_w, ff1wT, 1024, 8);
  wcvt<<<1024, 256, 0, stream>>>(ff2_w, ff2wT,  256, 10);

  for (int layer = 0; layer < NLAYERS; ++layer){
    // s2b = bf16(LN(h))
    ln_kernel<2><<<NR/4, 256, 0, stream>>>(h, ln1_g, ln1_b, nullptr, s2b);
    // qkv GEMM -> bf16 Q,K row-major + bf16 V^T
    {
      dim3 g(768/64, NR/128);
      mfma_gemm<0><<<g, 256, 0, stream>>>(s2b, qkvwT, qkv_b, nullptr,
                                          nullptr, qkbf, vTb, 768, 256);
    }
    // ProbSparse attention -> ob bf16
    attn_mfma<<<64*64, 256, 0, stream>>>(qkbf, vTb, ob_b);
    // tb = ob @ out_w + out_b + s2 (fp32)
    {
      dim3 g(256/64, NR/128);
      mfma_gemm<1><<<g, 256, 0, stream>>>(ob_b, outwT, out_b, s2b,
                                          tb, nullptr, nullptr, 256, 256);
    }
    // h += LN_a(tb); s2b = bf16(LN_2(h))
    lnln_kernel<<<NR/4, 256, 0, stream>>>(tb, lna_g, lna_b, ln2_g, ln2_b, h, s2b);
    // f = bf16(s2 @ ff1_w + ff1_b)
    {
      dim3 g(1024/64, NR/128);
      mfma_gemm<2><<<g, 256, 0, stream>>>(s2b, ff1wT, ff1_b, nullptr,
                                          nullptr, f, nullptr, 1024, 256);
    }
    // f *= std_L(f) in place
    vol_scale<<<B_*16, 512, 0, stream>>>(f);
    // h += f @ ff2_w + ff2_b
    {
      dim3 g(256/64, NR/128);
      mfma_gemm<3><<<g, 256, 0, stream>>>(f, ff2wT, ff2_b, nullptr,
                                          h, nullptr, nullptr, 256, 1024);
    }
  }
  // out = LN(h)
  ln_kernel<0><<<NR/4, 256, 0, stream>>>(h, lnf_g, lnf_b, out, nullptr);
}

// Round 5
// 1280.781 us; speedup vs baseline: 4.7794x; 1.0008x over previous
//
#include <hip/hip_runtime.h>
#include <hip/hip_bf16.h>
#include <math.h>

#define D_MODEL 256
#define NH 8
#define DFF 1024
#define NLAYERS 6
#define B_ 8
#define L_ 1024
#define NR (B_*L_)          // 8192 rows
#define TOPK 256            // L/4
#define LNEPS 1e-5f

typedef __attribute__((ext_vector_type(8))) short bf16x8;
typedef __attribute__((ext_vector_type(4))) float f32x4;

// ---------------- helpers ----------------
__device__ __forceinline__ float wsum(float v){
  #pragma unroll
  for(int o=32;o>0;o>>=1) v += __shfl_xor(v,o,64);
  return v;
}
__device__ __forceinline__ short f2bf(float x){
  unsigned u = __float_as_uint(x);
  u += 0x7fffu + ((u>>16)&1u);   // RNE (finite inputs only)
  return (short)(u>>16);
}
__device__ __forceinline__ float bf2f(short s){
  return __uint_as_float(((unsigned)(unsigned short)s)<<16);
}
// packed 2x f32 -> 2x bf16 (v_cvt_pk_bf16_f32 on gfx950)
__device__ __forceinline__ unsigned pk2bf(float a, float b){
  __hip_bfloat162 h = __float22bfloat162_rn(make_float2(a,b));
  unsigned u; __builtin_memcpy(&u, &h, 4);
  return u;
}
// bf16 raw bits -> 16-bit sortable key (order-isomorphic to float value)
__device__ __forceinline__ int sortkey(unsigned u){
  return (u & 0x8000u) ? (int)(u ^ 0xFFFFu) : (int)(u | 0x8000u);
}
// sortable key -> float value
__device__ __forceinline__ float kinvf(int k){
  unsigned u = (k & 0x8000) ? ((unsigned)k ^ 0x8000u) : ((unsigned)k ^ 0xFFFFu);
  return __uint_as_float(u << 16);
}
// async global->LDS, 16B per lane (dest = wave-uniform base + lane*16)
__device__ __forceinline__ void g2l(const short* g, short* l){
  __builtin_amdgcn_global_load_lds(
      (const __attribute__((address_space(1))) unsigned int*)g,
      (__attribute__((address_space(3))) unsigned int*)l,
      16, 0, 0);
}

// ---------------- embed: h = x@in_w + in_b + pe ----------------
__global__ __launch_bounds__(256) void embed_kernel(
    const float* __restrict__ x, const float* __restrict__ in_w,
    const float* __restrict__ in_b, float* __restrict__ h)
{
  int tid = blockIdx.x*256 + threadIdx.x;
  int n  = tid >> 6;
  int d0 = (tid & 63) << 2;
  int l  = n & (L_-1);
  float x0 = x[2*n], x1 = x[2*n+1];
  const float kf = -0.07195578415606394f;   // -ln(10000)/128
  float pe[4];
  #pragma unroll
  for(int ii=0; ii<2; ++ii){
    int i = (d0>>1) + ii;
    float dv  = expf((float)i * kf);
    float ang = (float)l * dv;
    pe[2*ii]   = sinf(ang);
    pe[2*ii+1] = cosf(ang);
  }
  float4 w0 = *(const float4*)(in_w + d0);
  float4 w1 = *(const float4*)(in_w + D_MODEL + d0);
  float4 bb = *(const float4*)(in_b + d0);
  float4 o;
  o.x = x0*w0.x + x1*w1.x + bb.x + pe[0];
  o.y = x0*w0.y + x1*w1.y + bb.y + pe[1];
  o.z = x0*w0.z + x1*w1.z + bb.z + pe[2];
  o.w = x0*w0.w + x1*w1.w + bb.w + pe[3];
  *(float4*)(h + (size_t)n*D_MODEL + d0) = o;
}

// ---------------- weight convert+transpose: WT[n][k] = bf16(W[k][n]) ----------------
__global__ __launch_bounds__(256) void wcvt(
    const float* __restrict__ W, short* __restrict__ WT, int N, int kshift)
{
  int idx = blockIdx.x*256 + threadIdx.x;
  int K = 1<<kshift;
  if (idx >= N*K) return;
  int n = idx >> kshift, k = idx & (K-1);
  WT[idx] = f2bf(W[(size_t)k*N + n]);
}

// ---------------- LayerNorm: wave per row ----------------
// OM: 0 = fp32 out, 2 = bf16 out only
template<int OM>
__global__ __launch_bounds__(256) void ln_kernel(
    const float* __restrict__ in, const float* __restrict__ g,
    const float* __restrict__ b, float* __restrict__ out,
    short* __restrict__ outb)
{
  int wave = threadIdx.x >> 6, lane = threadIdx.x & 63;
  int row = blockIdx.x*4 + wave;
  float4 v = ((const float4*)(in + (size_t)row*D_MODEL))[lane];
  float s  = v.x+v.y+v.z+v.w;
  float sq = v.x*v.x+v.y*v.y+v.z*v.z+v.w*v.w;
  s = wsum(s); sq = wsum(sq);
  float mean = s*(1.f/D_MODEL);
  float var  = sq*(1.f/D_MODEL) - mean*mean;
  float rstd = 1.f/sqrtf(var + LNEPS);
  float4 gv = ((const float4*)g)[lane];
  float4 bv = ((const float4*)b)[lane];
  float4 o;
  o.x = (v.x-mean)*rstd*gv.x + bv.x;
  o.y = (v.y-mean)*rstd*gv.y + bv.y;
  o.z = (v.z-mean)*rstd*gv.z + bv.z;
  o.w = (v.w-mean)*rstd*gv.w + bv.w;
  if (OM == 0){
    ((float4*)(out + (size_t)row*D_MODEL))[lane] = o;
  }
  if (OM == 2){
    uint2 pk; pk.x = pk2bf(o.x, o.y); pk.y = pk2bf(o.z, o.w);
    *(uint2*)(outb + (size_t)row*D_MODEL + lane*4) = pk;
  }
}

// ---------------- fused: h += LN_a(tb); s2b = bf16(LN_2(h)) ----------------
__global__ __launch_bounds__(256) void lnln_kernel(
    const float* __restrict__ tb,
    const float* __restrict__ ga, const float* __restrict__ ba,
    const float* __restrict__ g2, const float* __restrict__ b2,
    float* __restrict__ h, short* __restrict__ s2b)
{
  int wave = threadIdx.x >> 6, lane = threadIdx.x & 63;
  int row = blockIdx.x*4 + wave;
  float4 v = ((const float4*)(tb + (size_t)row*D_MODEL))[lane];
  float s  = v.x+v.y+v.z+v.w;
  float sq = v.x*v.x+v.y*v.y+v.z*v.z+v.w*v.w;
  s = wsum(s); sq = wsum(sq);
  float mean = s*(1.f/D_MODEL);
  float var  = sq*(1.f/D_MODEL) - mean*mean;
  float rstd = 1.f/sqrtf(var + LNEPS);
  float4 gv = ((const float4*)ga)[lane];
  float4 bv = ((const float4*)ba)[lane];
  float4* hp = (float4*)(h + (size_t)row*D_MODEL) + lane;
  float4 hv = *hp;
  float4 hn;
  hn.x = hv.x + (v.x-mean)*rstd*gv.x + bv.x;
  hn.y = hv.y + (v.y-mean)*rstd*gv.y + bv.y;
  hn.z = hv.z + (v.z-mean)*rstd*gv.z + bv.z;
  hn.w = hv.w + (v.w-mean)*rstd*gv.w + bv.w;
  *hp = hn;
  float s2  = hn.x+hn.y+hn.z+hn.w;
  float sq2 = hn.x*hn.x+hn.y*hn.y+hn.z*hn.z+hn.w*hn.w;
  s2 = wsum(s2); sq2 = wsum(sq2);
  float m2 = s2*(1.f/D_MODEL);
  float v2 = sq2*(1.f/D_MODEL) - m2*m2;
  float r2 = 1.f/sqrtf(v2 + LNEPS);
  float4 g2v = ((const float4*)g2)[lane];
  float4 b2v = ((const float4*)b2)[lane];
  uint2 pk;
  pk.x = pk2bf((hn.x-m2)*r2*g2v.x + b2v.x, (hn.y-m2)*r2*g2v.y + b2v.y);
  pk.y = pk2bf((hn.z-m2)*r2*g2v.z + b2v.z, (hn.w-m2)*r2*g2v.w + b2v.w);
  *(uint2*)(s2b + (size_t)row*D_MODEL + lane*4) = pk;
}

// ---------------- bf16 MFMA GEMM: C[M x N] = A[M x K] @ BT[N x K]^T ----------------
// tile TM x 128, BK=32, 256 thr = 4 waves; wave = (TM/4) x 128.
// MODE 0: qkv epilogue (Q/K row-major bf16 + V^T bf16), TM=128
// MODE 1: Cf = acc + bias + bf2f(residb)    (fp32 out)
// MODE 2: Cb = bf16(acc + bias)
// MODE 3: Cf += acc + bias                  (fp32 accumulate into h)
template<int MODE, int TM>
__global__ __launch_bounds__(256) void mfma_gemm(
    const short* __restrict__ A, const short* __restrict__ BT,
    const float* __restrict__ bias, const short* __restrict__ residb,
    float* __restrict__ Cf, short* __restrict__ Cb, short* __restrict__ Vt,
    int N, int K)
{
  constexpr int MT = TM/64;                    // 16-row m-tiles per wave
  __shared__ __align__(16) short As[TM*32];
  __shared__ __align__(16) short Bs[128*32];
  const int t = threadIdx.x, wv = t>>6, lane = t&63;
  const int r16 = lane&15, quad = lane>>4;
  const int m0 = blockIdx.y*TM, n0 = blockIdx.x*128;
  const short* Ab = A  + (size_t)m0*K;
  const short* Bb = BT + (size_t)n0*K;
  const f32x4 z = {0.f,0.f,0.f,0.f};
  f32x4 acc[MT][8];
  #pragma unroll
  for (int i=0;i<MT;++i)
    #pragma unroll
    for (int j=0;j<8;++j) acc[i][j] = z;

  for (int k0 = 0; k0 < K; k0 += 32){
    __syncthreads();
    #pragma unroll
    for (int j=0;j<MT;++j){
      int c = j*256 + wv*64 + lane;
      g2l(Ab + (size_t)(c>>2)*K + k0 + (c&3)*8, As + c*8);
    }
    #pragma unroll
    for (int j=0;j<2;++j){
      int c = j*256 + wv*64 + lane;
      g2l(Bb + (size_t)(c>>2)*K + k0 + (c&3)*8, Bs + c*8);
    }
    __syncthreads();
    bf16x8 af[MT];
    #pragma unroll
    for (int mt=0;mt<MT;++mt)
      af[mt] = *(const bf16x8*)(As + ((wv*MT*16 + mt*16 + r16)*32 + quad*8));
    bf16x8 bf[8];
    #pragma unroll
    for (int ct=0;ct<8;++ct)
      bf[ct] = *(const bf16x8*)(Bs + ((ct*16 + r16)*32 + quad*8));
    #pragma unroll
    for (int ct=0;ct<8;++ct)
      #pragma unroll
      for (int mt=0;mt<MT;++mt)
        acc[mt][ct] = __builtin_amdgcn_mfma_f32_16x16x32_bf16(af[mt], bf[ct], acc[mt][ct], 0,0,0);
  }

  #pragma unroll
  for (int mt=0;mt<MT;++mt){
    const int mb = m0 + wv*MT*16 + mt*16 + quad*4;
    #pragma unroll
    for (int ct=0;ct<8;++ct){
      const int n = n0 + ct*16 + r16;
      const float bv = bias[n];
      if (MODE == 0){
        if (n < 512){                    // Q or K: qkbf[region*64+bh][l][d]
          int region = n>>8, hh = (n>>5)&7, d = n&31;
          #pragma unroll
          for (int r=0;r<4;++r){
            int l = mb + r;
            size_t base = (((size_t)(region*64 + (l>>10)*8 + hh))*1024 + (l&1023))*32 + d;
            Cb[base] = f2bf(acc[mt][ct][r] + bv);
          }
        } else {                         // V transposed: vT[bh][d][l]
          int dv = n - 512, hh = dv>>5, d = dv&31;
          int b = mb>>10, lloc = mb&1023;
          size_t base = (((size_t)(b*8 + hh))*32 + d)*1024 + lloc;
          uint2 pk;
          pk.x = pk2bf(acc[mt][ct][0] + bv, acc[mt][ct][1] + bv);
          pk.y = pk2bf(acc[mt][ct][2] + bv, acc[mt][ct][3] + bv);
          *(uint2*)(Vt + base) = pk;
        }
      } else {
        #pragma unroll
        for (int r=0;r<4;++r){
          size_t off = (size_t)(mb + r)*N + n;
          float c = acc[mt][ct][r] + bv;
          if (MODE == 1) Cf[off] = c + bf2f(residb[off]);
          if (MODE == 2) Cb[off] = f2bf(c);
          if (MODE == 3) Cf[off] += c;
        }
      }
    }
  }
}

// ---------------- MFMA ProbSparse attention v3 ----------------
// Block = (bh, 16 q rows); XCD-pinned per head. Scores bf16 in LDS
// [row][key ^ s(row)], s(row)=(row&7)<<3 (8 distinct 4-bank shifts: PV b128
// reads and selection b32 reads are <=2-way). Selection: fixed 16-step
// bit-descent on 16-bit sortable keys (ballot+popcount, 2 rows interleaved,
// fully unrolled), fp32 softmax, normalized bf16 weights written back packed.
// LDS exactly 32 KB -> 5 blocks/CU.
__global__ __launch_bounds__(256,4) void attn_mfma(
    const short* __restrict__ qkbf, const short* __restrict__ vT,
    short* __restrict__ ob)
{
  __shared__ __align__(16) short sc16[16*1024];   // 32768 B exactly
  const int t = threadIdx.x, wv = t>>6, lane = t&63;
  const int r16 = lane&15, quad = lane>>4;
  const int blk = blockIdx.x;
  const int bh = (blk & 7)*8 + ((blk>>3)&7);   // head pinned to one XCD
  const int qt = blk >> 6;

  bf16x8 aq = *(const bf16x8*)(qkbf + ((size_t)bh*1024 + qt*16 + r16)*32 + quad*8);
  const short* kb = qkbf + (size_t)(64 + bh)*1024*32;

  // ---- QK: 16 key-tiles per wave ----
  bf16x8 bk[16];
  #pragma unroll
  for (int tt=0; tt<16; ++tt)
    bk[tt] = *(const bf16x8*)(kb + (size_t)(wv*256 + tt*16 + r16)*32 + quad*8);
  short* p0 = sc16 + quad*4096;        // rows quad*4..quad*4+3
  #pragma unroll
  for (int tt=0; tt<16; ++tt){
    f32x4 c = {0.f,0.f,0.f,0.f};
    c = __builtin_amdgcn_mfma_f32_16x16x32_bf16(aq, bk[tt], c, 0, 0, 0);
    const int keyq = (wv*256 + tt*16 + r16) ^ ((quad&1)<<5);  // ^(row&4)<<3
    unsigned u01 = pk2bf(c[0], c[1]);
    unsigned u23 = pk2bf(c[2], c[3]);
    p0[keyq]               = (short)u01;          // r=0
    p0[1024 + (keyq ^ 8)]  = (short)(u01>>16);    // r=1
    p0[2048 + (keyq ^ 16)] = (short)u23;          // r=2
    p0[3072 + (keyq ^ 24)] = (short)(u23>>16);    // r=3
  }
  __syncthreads();

  // ---- selection + softmax: wave wv owns rows 4wv..4wv+3, two pairs ----
  const float SC2 = 0.25500529485087056f;   // (1/sqrt(32)) * log2(e)
  #pragma unroll
  for (int rp=0; rp<2; ++rp){
    const int ra = wv*4 + rp*2;
    const int sa = (ra&7)<<3;                 // ra even
    short* pa = sc16 + ra*1024 + ((2*lane) ^ sa);
    short* pb = sc16 + (ra+1)*1024 + (((2*lane) ^ sa) ^ 8);
    unsigned wa[8], wb[8];
    #pragma unroll
    for (int i=0;i<8;++i){
      wa[i] = *(const unsigned*)(pa + i*128);
      wb[i] = *(const unsigned*)(pb + i*128);
    }
    int ka[16], kbk[16];
    #pragma unroll
    for (int i=0;i<8;++i){
      ka[2*i]    = sortkey(wa[i] & 0xFFFFu);
      ka[2*i+1]  = sortkey(wa[i] >> 16);
      kbk[2*i]   = sortkey(wb[i] & 0xFFFFu);
      kbk[2*i+1] = sortkey(wb[i] >> 16);
    }
    int mxa = ka[0], mxb = kbk[0];
    #pragma unroll
    for (int i=1;i<16;++i){
      mxa = (ka[i]  > mxa) ? ka[i]  : mxa;
      mxb = (kbk[i] > mxb) ? kbk[i] : mxb;
    }
    #pragma unroll
    for (int o=32;o>0;o>>=1){
      int sA = __shfl_xor(mxa, o, 64); mxa = (sA > mxa) ? sA : mxa;
      int sB = __shfl_xor(mxb, o, 64); mxb = (sB > mxb) ? sB : mxb;
    }
    // fixed 16-step bit-descent: loX = largest m with count(key>=m) >= TOPK
    int loA = 0, loB = 0;
    #pragma unroll
    for (int bit = 15; bit >= 0; --bit){
      const int midA = loA + (1<<bit);
      const int midB = loB + (1<<bit);
      int cA = 0, cB = 0;
      #pragma unroll
      for (int i=0;i<16;++i){
        cA += (int)__popcll(__ballot(ka[i]  >= midA));
        cB += (int)__popcll(__ballot(kbk[i] >= midB));
      }
      if (cA >= TOPK) loA = midA;
      if (cB >= TOPK) loB = midB;
    }
    const float thrA = kinvf(loA), thrB = kinvf(loB);
    const float nmA = -kinvf(mxa)*SC2, nmB = -kinvf(mxb)*SC2;
    float ea0[8], ea1[8], eb0[8], eb1[8];
    float suma = 0.f, sumb = 0.f;
    #pragma unroll
    for (int i=0;i<8;++i){
      float a0 = __uint_as_float(wa[i] << 16);
      float a1 = __uint_as_float(wa[i] & 0xFFFF0000u);
      float b0 = __uint_as_float(wb[i] << 16);
      float b1 = __uint_as_float(wb[i] & 0xFFFF0000u);
      ea0[i] = (a0 >= thrA) ? exp2f(fmaf(a0, SC2, nmA)) : 0.f;
      ea1[i] = (a1 >= thrA) ? exp2f(fmaf(a1, SC2, nmA)) : 0.f;
      eb0[i] = (b0 >= thrB) ? exp2f(fmaf(b0, SC2, nmB)) : 0.f;
      eb1[i] = (b1 >= thrB) ? exp2f(fmaf(b1, SC2, nmB)) : 0.f;
      suma += ea0[i] + ea1[i]; sumb += eb0[i] + eb1[i];
    }
    suma = wsum(suma); sumb = wsum(sumb);
    const float inva = 1.f/suma, invb = 1.f/sumb;
    #pragma unroll
    for (int i=0;i<8;++i){
      *(unsigned*)(pa + i*128) = pk2bf(ea0[i]*inva, ea1[i]*inva);
      *(unsigned*)(pb + i*128) = pk2bf(eb0[i]*invb, eb1[i]*invb);
    }
  }
  __syncthreads();

  // ---- PV: wave wv covers keys wv*256..+255 ----
  const short* vb = vT + (size_t)bh*32*1024;
  bf16x8 bvv[16];
  #pragma unroll
  for (int tt=0; tt<8; ++tt){
    int k0 = wv*256 + tt*32;
    #pragma unroll
    for (int n=0;n<2;++n)
      bvv[tt*2+n] = *(const bf16x8*)(vb + (size_t)(n*16 + r16)*1024 + k0 + quad*8);
  }
  const int sA = (r16&7) << 3;         // s(row=r16)
  f32x4 oa0 = {0.f,0.f,0.f,0.f}, oa1 = {0.f,0.f,0.f,0.f};
  #pragma unroll
  for (int tt=0; tt<8; ++tt){
    int k0 = wv*256 + tt*32;
    bf16x8 af = *(const bf16x8*)(sc16 + r16*1024 + ((k0 + quad*8) ^ sA));
    oa0 = __builtin_amdgcn_mfma_f32_16x16x32_bf16(af, bvv[tt*2+0], oa0, 0, 0, 0);
    oa1 = __builtin_amdgcn_mfma_f32_16x16x32_bf16(af, bvv[tt*2+1], oa1, 0, 0, 0);
  }
  __syncthreads();
  float* po = (float*)sc16;            // 8 KB partials [wave][16q][32d]
  #pragma unroll
  for (int r=0;r<4;++r){
    po[wv*512 + (quad*4+r)*32 +      r16] = oa0[r];
    po[wv*512 + (quad*4+r)*32 + 16 + r16] = oa1[r];
  }
  __syncthreads();
  int e = t*2;
  float v0 = po[e]   + po[512+e]   + po[1024+e]   + po[1536+e];
  float v1 = po[e+1] + po[512+e+1] + po[1024+e+1] + po[1536+e+1];
  int q = e>>5, d = e&31;
  int b = bh>>3, hh = bh&7;
  size_t off = ((size_t)(b*1024 + qt*16 + q))*256 + hh*32 + d;
  *(unsigned*)(ob + off) = pk2bf(v0, v1);
}

// ---------------- Volatilite: f *= std_L(f), in place (bf16) ----------------
__global__ __launch_bounds__(512) void vol_scale(short* __restrict__ f)
{
  __shared__ float ps[8][64], pq[8][64], vs[64];
  int b = blockIdx.x >> 4, cb = blockIdx.x & 15;
  int cl = threadIdx.x & 63, sl = threadIdx.x >> 6;   // 8 waves x 128 L each
  int col = cb*64 + cl;
  short* fb = f + (size_t)b*L_*DFF + col;
  float s = 0.f, sq = 0.f;
  for (int l = sl*128; l < sl*128+128; ++l){
    float v = bf2f(fb[(size_t)l*DFF]);
    s += v; sq += v*v;
  }
  ps[sl][cl] = s; pq[sl][cl] = sq;
  __syncthreads();
  if (threadIdx.x < 64){
    float st=0.f, qt=0.f;
    #pragma unroll
    for (int i=0;i<8;++i){ st += ps[i][cl]; qt += pq[i][cl]; }
    float mean = st*(1.f/L_);
    float var  = qt*(1.f/L_) - mean*mean;
    vs[cl] = sqrtf(fmaxf(var, 0.f));
  }
  __syncthreads();
  float vv = vs[cl];
  for (int l = sl*128; l < sl*128+128; ++l){
    size_t o = (size_t)l*DFF;
    fb[o] = f2bf(bf2f(fb[o]) * vv);
  }
}

// ---------------- launch ----------------
extern "C" void kernel_launch(void* const* d_in, const int* in_sizes, int n_in,
                              void* d_out, int out_size, void* d_ws, size_t ws_size,
                              hipStream_t stream) {
  const float* x     = (const float*)d_in[0];
  const float* in_w  = (const float*)d_in[1];
  const float* in_b  = (const float*)d_in[2];
  const float* ln1_g = (const float*)d_in[3];
  const float* ln1_b = (const float*)d_in[4];
  const float* qkv_w = (const float*)d_in[5];
  const float* qkv_b = (const float*)d_in[6];
  const float* out_w = (const float*)d_in[7];
  const float* out_b = (const float*)d_in[8];
  const float* lna_g = (const float*)d_in[9];
  const float* lna_b = (const float*)d_in[10];
  const float* ln2_g = (const float*)d_in[11];
  const float* ln2_b = (const float*)d_in[12];
  const float* ff1_w = (const float*)d_in[13];
  const float* ff1_b = (const float*)d_in[14];
  const float* ff2_w = (const float*)d_in[15];
  const float* ff2_b = (const float*)d_in[16];
  const float* lnf_g = (const float*)d_in[17];
  const float* lnf_b = (const float*)d_in[18];
  float* out = (float*)d_out;

  // ws layout (~37.6 MB):
  //  h @0 8M | s2b @8M 4M | qkbf @12M 8M | vTb @20M 4M | ob_b @24M 4M
  //  f @12M 16M (aliases qkbf/vTb/ob_b — dead at ff1 time) | tb @28M 8M
  //  weights @36M
  char* ws = (char*)d_ws;
  float* h     = (float*)(ws);
  short* s2b   = (short*)(ws + (size_t)( 8<<20));
  short* qkbf  = (short*)(ws + (size_t)(12<<20));
  short* vTb   = (short*)(ws + (size_t)(20<<20));
  short* ob_b  = (short*)(ws + (size_t)(24<<20));
  short* f     = (short*)(ws + (size_t)(12<<20));
  float* tb    = (float*)(ws + (size_t)(28<<20));
  short* qkvwT = (short*)(ws + (size_t)(36<<20));
  short* outwT = (short*)(ws + (size_t)(36<<20) + 393216);
  short* ff1wT = (short*)(ws + (size_t)(36<<20) + 393216 + 131072);
  short* ff2wT = (short*)(ws + (size_t)(36<<20) + 393216 + 131072 + 524288);

  embed_kernel<<<NR*64/256, 256, 0, stream>>>(x, in_w, in_b, h);
  wcvt<<< 768, 256, 0, stream>>>(qkv_w, qkvwT,  768, 8);
  wcvt<<< 256, 256, 0, stream>>>(out_w, outwT,  256, 8);
  wcvt<<<1024, 256, 0, stream>>>(ff1_w, ff1wT, 1024, 8);
  wcvt<<<1024, 256, 0, stream>>>(ff2_w, ff2wT,  256, 10);

  for (int layer = 0; layer < NLAYERS; ++layer){
    // s2b = bf16(LN(h))
    ln_kernel<2><<<NR/4, 256, 0, stream>>>(h, ln1_g, ln1_b, nullptr, s2b);
    // qkv GEMM -> bf16 Q,K row-major + bf16 V^T
    {
      dim3 g(768/128, NR/128);
      mfma_gemm<0,128><<<g, 256, 0, stream>>>(s2b, qkvwT, qkv_b, nullptr,
                                              nullptr, qkbf, vTb, 768, 256);
    }
    // ProbSparse attention -> ob bf16
    attn_mfma<<<64*64, 256, 0, stream>>>(qkbf, vTb, ob_b);
    // tb = ob @ out_w + out_b + s2 (fp32)
    {
      dim3 g(256/128, NR/64);
      mfma_gemm<1,64><<<g, 256, 0, stream>>>(ob_b, outwT, out_b, s2b,
                                             tb, nullptr, nullptr, 256, 256);
    }
    // h += LN_a(tb); s2b = bf16(LN_2(h))
    lnln_kernel<<<NR/4, 256, 0, stream>>>(tb, lna_g, lna_b, ln2_g, ln2_b, h, s2b);
    // f = bf16(s2 @ ff1_w + ff1_b)
    {
      dim3 g(1024/128, NR/128);
      mfma_gemm<2,128><<<g, 256, 0, stream>>>(s2b, ff1wT, ff1_b, nullptr,
                                              nullptr, f, nullptr, 1024, 256);
    }
    // f *= std_L(f) in place
    vol_scale<<<B_*16, 512, 0, stream>>>(f);
    // h += f @ ff2_w + ff2_b
    {
      dim3 g(256/128, NR/64);
      mfma_gemm<3,64><<<g, 256, 0, stream>>>(f, ff2wT, ff2_b, nullptr,
                                             h, nullptr, nullptr, 256, 1024);
    }
  }
  // out = LN(h)
  ln_kernel<0><<<NR/4, 256, 0, stream>>>(h, lnf_g, lnf_b, out, nullptr);
}